// Round 12
// baseline (1961.205 us; speedup 1.0000x reference)
//
#include <hip/hip_runtime.h>
#include <math.h>

#define HF 128
#define NB 9216          // nodes per batch (96*96)
#define BB 2
#define MROWS (BB*NB)    // 18432
#define GH 96
#define GW 96
#define LAYERS 6

typedef __attribute__((ext_vector_type(8))) short bf16x8;
typedef __attribute__((ext_vector_type(4))) float f32x4;

#define MFMA16(a, b, c) __builtin_amdgcn_mfma_f32_16x16x32_bf16(a, b, c, 0, 0, 0)

__device__ __forceinline__ float swishf(float x) {
    return __fdividef(x, 1.0f + __expf(-x));
}

// fp32 -> bf16 bits, round-to-nearest-even
__device__ __forceinline__ unsigned short f2b(float f) {
    unsigned u = __float_as_uint(f);
    unsigned r = (u + 0x7fffu + ((u >> 16) & 1u)) >> 16;
    return (unsigned short)r;
}
__device__ __forceinline__ float b2f(unsigned short u) {
    return __uint_as_float((unsigned)u << 16);
}

// normalize 8 hf values -> bf16x8 fragment
__device__ __forceinline__ bf16x8 norm_frag(const float* __restrict__ hp,
                                            const float* __restrict__ mus,
                                            const float* __restrict__ rss, int k0) {
    float4 h0 = *(const float4*)hp;
    float4 h1 = *(const float4*)(hp + 4);
    float4 m0 = *(const float4*)&mus[k0];
    float4 m1 = *(const float4*)&mus[k0 + 4];
    float4 r0 = *(const float4*)&rss[k0];
    float4 r1 = *(const float4*)&rss[k0 + 4];
    union { bf16x8 v; unsigned u[4]; } az;
    float a0 = (h0.x - m0.x) * r0.x, a1 = (h0.y - m0.y) * r0.y;
    az.u[0] = (unsigned)f2b(a0) | ((unsigned)f2b(a1) << 16);
    float a2 = (h0.z - m0.z) * r0.z, a3 = (h0.w - m0.w) * r0.w;
    az.u[1] = (unsigned)f2b(a2) | ((unsigned)f2b(a3) << 16);
    float a4 = (h1.x - m1.x) * r1.x, a5 = (h1.y - m1.y) * r1.y;
    az.u[2] = (unsigned)f2b(a4) | ((unsigned)f2b(a5) << 16);
    float a6 = (h1.z - m1.z) * r1.z, a7 = (h1.w - m1.w) * r1.w;
    az.u[3] = (unsigned)f2b(a6) | ((unsigned)f2b(a7) << 16);
    return az.v;
}

// finalize instance-norm stats in LDS (mraw=nullptr -> identity)
__device__ __forceinline__ void load_musig(const float* __restrict__ mraw, int b, int t,
                                           float* __restrict__ mus, float* __restrict__ rss) {
    if (t < 128) {
        float mu = 0.f, rs = 1.f;
        if (mraw) {
            float s = mraw[b * 128 + t], q = mraw[256 + b * 128 + t];
            mu = s * (1.0f / NB);
            float var = q * (1.0f / NB) - mu * mu;
            rs = rsqrtf(var + 1e-5f);
        }
        mus[t] = mu; rss[t] = rs;
    }
}

// ---------------- weight prep: wT[slot][col][k] = bf16(W[k][col]) ----------------
// slots: 0=emb_w2, 1=out_w1, 2+6l+{0..5} = msgW1a, msgW1b, msgW2, updW1a, updW1b, updW2
__global__ void k_prep(const float* __restrict__ embw2, const float* __restrict__ outw1,
                       const float* __restrict__ msgw1, const float* __restrict__ msgw2,
                       const float* __restrict__ updw1, const float* __restrict__ updw2,
                       unsigned short* __restrict__ wT) {
    int s = blockIdx.x;
    const float* src;
    if (s == 0) src = embw2;
    else if (s == 1) src = outw1;
    else {
        int l = (s - 2) / 6, r = (s - 2) % 6;
        if (r == 0)      src = msgw1 + (size_t)l * 269 * HF;
        else if (r == 1) src = msgw1 + (size_t)l * 269 * HF + HF * HF;
        else if (r == 2) src = msgw2 + (size_t)l * HF * HF;
        else if (r == 3) src = updw1 + (size_t)l * 256 * HF;
        else if (r == 4) src = updw1 + (size_t)l * 256 * HF + HF * HF;
        else             src = updw2 + (size_t)l * HF * HF;
    }
    __shared__ float tile[128][133];
    int t = threadIdx.x;
#pragma unroll
    for (int i = 0; i < 64; ++i) {
        int id = i * 256 + t;
        tile[id >> 7][id & 127] = src[id];
    }
    __syncthreads();
    unsigned short* o = wT + (size_t)s * 16384;
#pragma unroll
    for (int i = 0; i < 64; ++i) {
        int id = i * 256 + t;
        int col = id >> 7, k = id & 127;
        o[id] = f2b(tile[k][col]);
    }
}

// ---------------- build nodein [B,N,16]; zero stat accumulators ----------------
__global__ void k_build(const float* __restrict__ x, const float* __restrict__ pos,
                        float* __restrict__ nodein, float* __restrict__ msr) {
    int idx = blockIdx.x * 256 + threadIdx.x;
    if (idx < LAYERS * 512) msr[idx] = 0.0f;
    if (idx >= MROWS) return;
    int b = idx / NB, n = idx - b * NB;
    float* o = nodein + (size_t)idx * 16;
    const float* xb = x + (size_t)b * 12 * NB + n;
#pragma unroll
    for (int k = 0; k < 12; ++k) o[k] = xb[(size_t)k * NB];
    o[12] = pos[2 * n];
    o[13] = pos[2 * n + 1];
    o[14] = 0.0f; o[15] = 0.0f;
}

// ---------------- fused embedding: t1 = swish(nodein@W1+b1); hf = swish(t1@W2+b2) ----------------
__global__ __launch_bounds__(256, 4)
void k_emb(const float* __restrict__ nodein, const float* __restrict__ w1,
           const float* __restrict__ b1, const unsigned short* __restrict__ wT2,
           const float* __restrict__ b2, float* __restrict__ hf) {
    __shared__ float xs[16][14];
    __shared__ char t1s[4096];
    int t = threadIdx.x;
    int rt = blockIdx.x * 16;
    if (t < 224) {
        int r = t / 14, k = t - r * 14;
        xs[r][k] = nodein[(size_t)(rt + r) * 16 + k];
    }
    __syncthreads();
    {
        int f = t & 127, rblk = t >> 7;
        float wreg[14];
#pragma unroll
        for (int k = 0; k < 14; ++k) wreg[k] = w1[k * HF + f];
        float bv = b1[f];
#pragma unroll
        for (int i = 0; i < 8; ++i) {
            int row = rblk * 8 + i;
            float acc = bv;
#pragma unroll
            for (int k = 0; k < 14; ++k) acc = fmaf(xs[row][k], wreg[k], acc);
            int addr = (row * 256 + f * 2) ^ ((row & 7) << 4);
            *(unsigned short*)(t1s + addr) = f2b(swishf(acc));
        }
    }
    __syncthreads();
    int wave = t >> 6, lane = t & 63, lr = lane & 15, lg = lane >> 4;
    int fb = wave * 32;
    f32x4 acc[2];
    acc[0] = (f32x4)0.0f; acc[1] = (f32x4)0.0f;
#pragma unroll
    for (int kc = 0; kc < 4; ++kc) {
        int k0 = kc * 32 + lg * 8;
        bf16x8 a = *(const bf16x8*)(t1s + ((lr * 256 + k0 * 2) ^ ((lr & 7) << 4)));
#pragma unroll
        for (int j = 0; j < 2; ++j) {
            bf16x8 b = *(const bf16x8*)(wT2 + (size_t)(fb + j * 16 + lr) * HF + k0);
            acc[j] = MFMA16(a, b, acc[j]);
        }
    }
#pragma unroll
    for (int j = 0; j < 2; ++j) {
        int f = fb + j * 16 + lr;
        float bv = b2[f];
#pragma unroll
        for (int r = 0; r < 4; ++r) {
            size_t o = (size_t)(rt + lg * 4 + r) * HF + f;
            hf[o] = swishf(acc[j][r] + bv);
        }
    }
}

// ---------------- A/S projection (norm-on-read) with fused Au ----------------
// A = bf16(norm(hf)@W1a + nodein@W1u) ; S = bf16(norm(hf)@W1b - nodein@W1u)
__global__ __launch_bounds__(256, 8)
void k_as(const float* __restrict__ hf, const float* __restrict__ mraw,
          const unsigned short* __restrict__ wA, const unsigned short* __restrict__ wB,
          const float* __restrict__ nodein, const float* __restrict__ w1u,
          unsigned short* __restrict__ A, unsigned short* __restrict__ S) {
    __shared__ float w1s[12][128];
    __shared__ float nis[16][12];
    __shared__ float mus[128], rss[128];
    int t = threadIdx.x, wave = t >> 6, lane = t & 63, lr = lane & 15, lg = lane >> 4;
    int rt = blockIdx.x * 16;
    int b = blockIdx.x / (NB / 16);
    int fb = wave * 32;
    for (int i = t; i < 12 * 128; i += 256) w1s[i >> 7][i & 127] = w1u[i];
    if (t < 192) {
        int r = t / 12, k = t - (t / 12) * 12;
        nis[r][k] = nodein[(size_t)(rt + r) * 16 + k];
    }
    load_musig(mraw, b, t, mus, rss);
    __syncthreads();
    f32x4 accA[2], accS[2];
    accA[0] = (f32x4)0.0f; accA[1] = (f32x4)0.0f;
    accS[0] = (f32x4)0.0f; accS[1] = (f32x4)0.0f;
#pragma unroll
    for (int kc = 0; kc < 4; ++kc) {
        int k0 = kc * 32 + lg * 8;
        bf16x8 a = norm_frag(hf + (size_t)(rt + lr) * HF + k0, mus, rss, k0);
#pragma unroll
        for (int j = 0; j < 2; ++j) {
            bf16x8 bA = *(const bf16x8*)(wA + (size_t)(fb + j * 16 + lr) * HF + k0);
            accA[j] = MFMA16(a, bA, accA[j]);
            bf16x8 bS = *(const bf16x8*)(wB + (size_t)(fb + j * 16 + lr) * HF + k0);
            accS[j] = MFMA16(a, bS, accS[j]);
        }
    }
#pragma unroll
    for (int j = 0; j < 2; ++j) {
        int f = fb + j * 16 + lr;
        float au[4] = {0.f, 0.f, 0.f, 0.f};
#pragma unroll
        for (int k = 0; k < 12; ++k) {
            float wv = w1s[k][f];
#pragma unroll
            for (int r = 0; r < 4; ++r) au[r] = fmaf(nis[lg * 4 + r][k], wv, au[r]);
        }
#pragma unroll
        for (int r = 0; r < 4; ++r) {
            size_t o = (size_t)(rt + lg * 4 + r) * HF + f;
            A[o] = f2b(accA[j][r] + au[r]);
            S[o] = f2b(accS[j][r] - au[r]);
        }
    }
}

// ---------------- fused message+aggregate+update (3-offset groups, small LDS):
// agg = (1/deg) sum_off swish(swish(A+S+D)@W2m + b2m)
// t1  = swish(norm(hf)@W1a + agg@W1b + b1u)
// v   = swish(t1@W2u + b2u) + norm(hf); hf <- v; stats -> atomicAdd msr ----------------
__global__ __launch_bounds__(256, 8)
void k_aggupd(const unsigned short* __restrict__ Ab, const unsigned short* __restrict__ Sb,
              const unsigned short* __restrict__ wT2, const float* __restrict__ b2m,
              const float* __restrict__ b1m, const float* __restrict__ w1d,
              float* __restrict__ hf, const float* __restrict__ mraw,
              const unsigned short* __restrict__ w1a, const unsigned short* __restrict__ w1b,
              const unsigned short* __restrict__ w2u, const float* __restrict__ b1u,
              const float* __restrict__ b2u, float* __restrict__ msr) {
    __shared__ float dsb[3][128];
    __shared__ float mus[128], rss[128];
    __shared__ char exb[3 * 4096];       // 3-offset z groups; phase3: agg @0, t1 @4096
    int t = threadIdx.x, kq = t >> 6, lane = t & 63, lr = lane & 15, lg = lane >> 4;
    int bx = blockIdx.x;
    int b = bx / (NB / 16), tile = bx % (NB / 16);
    int rt = tile * 16;                  // LOCAL row within batch (16 | 96)
    int fb = kq * 32;
    size_t bN = (size_t)b * NB;
    int R = rt / GW, C0 = rt % GW;
    bool interior = (R > 0) && (R < GH - 1) && (C0 > 0) && (C0 + 16 < GW);

    if (t < 128) {
        float bb = b1m[t], wd = w1d[t];
        dsb[0][t] = bb;
        dsb[1][t] = fmaf(1.0f / 95.0f, wd, bb);
        dsb[2][t] = fmaf(1.4142135623730951f / 95.0f, wd, bb);
    }
    load_musig(mraw, b, t, mus, rss);
    bf16x8 w2f[2][4];
#pragma unroll
    for (int j = 0; j < 2; ++j)
#pragma unroll
        for (int kc = 0; kc < 4; ++kc)
            w2f[j][kc] = *(const bf16x8*)(wT2 + (size_t)(fb + j * 16 + lr) * HF
                                          + kc * 32 + lg * 8);
    int rowA = rt + lr;
    float Af[8];
    {
        bf16x8 av = *(const bf16x8*)(Ab + (bN + rowA) * HF + kq * 32 + lg * 8);
#pragma unroll
        for (int e = 0; e < 8; ++e) Af[e] = b2f((unsigned short)av[e]);
    }
    float b2r[2] = { b2m[fb + lr], b2m[fb + 16 + lr] };
    int lofs = lane * 16;
    __syncthreads();   // dsb/mus ready

    f32x4 agg2[2];
    agg2[0] = (f32x4)0.0f; agg2[1] = (f32x4)0.0f;
    bf16x8 sv;
    {
        int src = rowA - 97;
        if (!interior) src = min(max(src, 0), NB - 1);
        sv = *(const bf16x8*)(Sb + (bN + src) * HF + kq * 32 + lg * 8);
    }
#pragma unroll
    for (int g = 0; g < 3; ++g) {
        // ---- z for offsets 3g..3g+2 (own k-quarter) ----
#pragma unroll
        for (int oi = 0; oi < 3; ++oi) {
            int off = g * 3 + oi;
            int dr = off / 3 - 1, dc = off % 3 - 1;
            int dd = dr * dr + dc * dc;
            bf16x8 cur = sv;
            if (off < 8) {
                int no = off + 1;
                int dnn = (no / 3 - 1) * GW + (no % 3 - 1);
                int src = rowA + dnn;
                if (!interior) src = min(max(src, 0), NB - 1);
                sv = *(const bf16x8*)(Sb + (bN + src) * HF + kq * 32 + lg * 8);
            }
            const float* dp = &dsb[dd][kq * 32 + lg * 8];
            union { bf16x8 v; unsigned u[4]; } cu; cu.v = cur;
            union { bf16x8 v; unsigned u[4]; } az;
#pragma unroll
            for (int q = 0; q < 4; ++q) {
                float sl = __uint_as_float(cu.u[q] << 16);
                float sh = __uint_as_float(cu.u[q] & 0xffff0000u);
                float zl = swishf(Af[2 * q]     + sl + dp[2 * q]);
                float zh = swishf(Af[2 * q + 1] + sh + dp[2 * q + 1]);
                az.u[q] = (unsigned)f2b(zl) | ((unsigned)f2b(zh) << 16);
            }
            *(bf16x8*)(exb + oi * 4096 + kq * 1024 + lofs) = az.v;
        }
        __syncthreads();
        // ---- MFMA + epilogue for offsets 3g..3g+2 ----
#pragma unroll
        for (int oi = 0; oi < 3; ++oi) {
            int off = g * 3 + oi;
            int dr = off / 3 - 1, dc = off % 3 - 1;
            f32x4 acc[2];
            acc[0] = (f32x4)0.0f; acc[1] = (f32x4)0.0f;
#pragma unroll
            for (int kc = 0; kc < 4; ++kc) {
                bf16x8 a = *(const bf16x8*)(exb + oi * 4096 + kc * 1024 + lofs);
                acc[0] = MFMA16(a, w2f[0][kc], acc[0]);
                acc[1] = MFMA16(a, w2f[1][kc], acc[1]);
            }
            if (interior) {
#pragma unroll
                for (int j = 0; j < 2; ++j)
#pragma unroll
                    for (int r = 0; r < 4; ++r)
                        agg2[j][r] += swishf(acc[j][r] + b2r[j]);
            } else {
                bool rOK = (unsigned)(R + dr) < (unsigned)GH;
#pragma unroll
                for (int j = 0; j < 2; ++j)
#pragma unroll
                    for (int r = 0; r < 4; ++r) {
                        int C = C0 + lg * 4 + r;
                        if (rOK && (unsigned)(C + dc) < (unsigned)GW)
                            agg2[j][r] += swishf(acc[j][r] + b2r[j]);
                    }
            }
        }
        __syncthreads();
    }

    // ---- agg tile -> LDS (bf16, swizzled, rows local 0..15) ----
#pragma unroll
    for (int j = 0; j < 2; ++j)
#pragma unroll
        for (int r = 0; r < 4; ++r) {
            int row = lg * 4 + r;
            float v;
            if (interior) {
                v = agg2[j][r] * (1.0f / 9.0f);
            } else {
                float nr = 1.0f + (R > 0) + (R < GH - 1);
                int C = C0 + row;
                float nc = 1.0f + (C > 0) + (C < GW - 1);
                v = __fdividef(agg2[j][r], nr * nc);
            }
            int f = fb + j * 16 + lr;
            int addr = (row * 256 + f * 2) ^ ((row & 7) << 4);
            *(unsigned short*)(exb + addr) = f2b(v);
        }
    __syncthreads();

    // ---- update GEMM1 (norm(hf), agg) — hf rows are GLOBAL (bN + rt) ----
    f32x4 acc[2];
    acc[0] = (f32x4)0.0f; acc[1] = (f32x4)0.0f;
#pragma unroll
    for (int kc = 0; kc < 4; ++kc) {
        int k0 = kc * 32 + lg * 8;
        bf16x8 a1 = norm_frag(hf + (bN + rt + lr) * HF + k0, mus, rss, k0);
        bf16x8 a2 = *(const bf16x8*)(exb + ((lr * 256 + k0 * 2) ^ ((lr & 7) << 4)));
#pragma unroll
        for (int j = 0; j < 2; ++j) {
            bf16x8 bA = *(const bf16x8*)(w1a + (size_t)(fb + j * 16 + lr) * HF + k0);
            acc[j] = MFMA16(a1, bA, acc[j]);
            bf16x8 bB = *(const bf16x8*)(w1b + (size_t)(fb + j * 16 + lr) * HF + k0);
            acc[j] = MFMA16(a2, bB, acc[j]);
        }
    }
    // t1 = swish(acc + b1u) -> swizzled LDS @4096
#pragma unroll
    for (int j = 0; j < 2; ++j) {
        int col = fb + j * 16 + lr;
        float bv = b1u[col];
#pragma unroll
        for (int r = 0; r < 4; ++r) {
            int row = lg * 4 + r;
            int addr = (row * 256 + col * 2) ^ ((row & 7) << 4);
            *(unsigned short*)(exb + 4096 + addr) = f2b(swishf(acc[j][r] + bv));
        }
    }
    __syncthreads();
    // GEMM2
    f32x4 acc2[2];
    acc2[0] = (f32x4)0.0f; acc2[1] = (f32x4)0.0f;
#pragma unroll
    for (int kc = 0; kc < 4; ++kc) {
        int k0 = kc * 32 + lg * 8;
        bf16x8 a = *(const bf16x8*)(exb + 4096 + ((lr * 256 + k0 * 2) ^ ((lr & 7) << 4)));
#pragma unroll
        for (int j = 0; j < 2; ++j) {
            bf16x8 bfr = *(const bf16x8*)(w2u + (size_t)(fb + j * 16 + lr) * HF + k0);
            acc2[j] = MFMA16(a, bfr, acc2[j]);
        }
    }
#pragma unroll
    for (int j = 0; j < 2; ++j) {
        int f = fb + j * 16 + lr;
        float bv = b2u[f];
        float mu = mus[f], rs = rss[f];
        float s1 = 0.f, s2 = 0.f;
#pragma unroll
        for (int r = 0; r < 4; ++r) {
            size_t o = (bN + rt + lg * 4 + r) * HF + f;
            float v = swishf(acc2[j][r] + bv) + (hf[o] - mu) * rs;
            hf[o] = v;
            s1 += v; s2 += v * v;
        }
        s1 += __shfl_xor(s1, 16); s1 += __shfl_xor(s1, 32);
        s2 += __shfl_xor(s2, 16); s2 += __shfl_xor(s2, 32);
        if (lg == 0) {
            atomicAdd(&msr[b * 128 + f], s1);
            atomicAdd(&msr[256 + b * 128 + f], s2);
        }
    }
}

// ---------------- fused output head (norm-on-read):
// g1 = swish(norm(hf)@W1+b1); out = x[:,-1] + g1@W2 + b2 ----------------
__global__ __launch_bounds__(256, 4)
void k_out(const float* __restrict__ hf, const float* __restrict__ mraw,
           const unsigned short* __restrict__ wT1, const float* __restrict__ b1,
           const float* __restrict__ w2, const float* __restrict__ b2,
           const float* __restrict__ x, float* __restrict__ out) {
    __shared__ float g1s[16][132];
    __shared__ float w2s[384];
    __shared__ float mus[128], rss[128];
    int t = threadIdx.x, wave = t >> 6, lane = t & 63, lr = lane & 15, lg = lane >> 4;
    int rt = blockIdx.x * 16;
    int b = blockIdx.x / (NB / 16);
    int fb = wave * 32;
    for (int i = t; i < 384; i += 256) w2s[i] = w2[i];
    load_musig(mraw, b, t, mus, rss);
    __syncthreads();
    f32x4 acc[2];
    acc[0] = (f32x4)0.0f; acc[1] = (f32x4)0.0f;
#pragma unroll
    for (int kc = 0; kc < 4; ++kc) {
        int k0 = kc * 32 + lg * 8;
        bf16x8 a = norm_frag(hf + (size_t)(rt + lr) * HF + k0, mus, rss, k0);
#pragma unroll
        for (int j = 0; j < 2; ++j) {
            bf16x8 bfr = *(const bf16x8*)(wT1 + (size_t)(fb + j * 16 + lr) * HF + k0);
            acc[j] = MFMA16(a, bfr, acc[j]);
        }
    }
#pragma unroll
    for (int j = 0; j < 2; ++j) {
        int f = fb + j * 16 + lr;
        float bv = b1[f];
#pragma unroll
        for (int r = 0; r < 4; ++r)
            g1s[lg * 4 + r][f] = swishf(acc[j][r] + bv);
    }
    __syncthreads();
    if (t < 48) {
        int r = t / 3, c = t - (t / 3) * 3;
        int row = rt + r;
        int bb = row / NB, n = row - bb * NB;
        float a = b2[c];
#pragma unroll 8
        for (int k = 0; k < HF; ++k) a = fmaf(g1s[r][k], w2s[k * 3 + c], a);
        float xv = x[(((size_t)bb * 4 + 3) * 3 + c) * NB + n];
        out[((size_t)bb * 3 + c) * NB + n] = a + xv;
    }
}

extern "C" void kernel_launch(void* const* d_in, const int* in_sizes, int n_in,
                              void* d_out, int out_size, void* d_ws, size_t ws_size,
                              hipStream_t stream) {
    const float* x      = (const float*)d_in[0];
    const float* pos    = (const float*)d_in[3];
    const float* emb_w1 = (const float*)d_in[4];
    const float* emb_b1 = (const float*)d_in[5];
    const float* emb_b2 = (const float*)d_in[7];
    const float* msg_w1 = (const float*)d_in[8];
    const float* msg_b1 = (const float*)d_in[9];
    const float* msg_b2 = (const float*)d_in[11];
    const float* upd_b1 = (const float*)d_in[13];
    const float* upd_b2 = (const float*)d_in[15];
    const float* out_b1 = (const float*)d_in[17];
    const float* out_w2 = (const float*)d_in[18];
    const float* out_b2 = (const float*)d_in[19];

    float* w = (float*)d_ws;
    size_t off = 0;
    auto alloc = [&](size_t n) { float* p = w + off; off += n; return p; };
    float* nodein  = alloc((size_t)MROWS * 16);
    float* hf      = alloc((size_t)MROWS * HF);
    float* msr     = alloc((size_t)LAYERS * 512);   // per-layer [sum|sumsq] accumulators
    unsigned short* Abf  = (unsigned short*)alloc((size_t)MROWS * 64);
    unsigned short* Sbf  = (unsigned short*)alloc((size_t)MROWS * 64);
    unsigned short* wT   = (unsigned short*)alloc((size_t)38 * 16384 / 2);
    (void)ws_size; (void)in_sizes; (void)n_in; (void)out_size;

    k_prep<<<38, 256, 0, stream>>>((const float*)d_in[6], (const float*)d_in[16],
                                   msg_w1, (const float*)d_in[10],
                                   (const float*)d_in[12], (const float*)d_in[14], wT);
    k_build<<<(MROWS + 255) / 256, 256, 0, stream>>>(x, pos, nodein, msr);
    k_emb<<<1152, 256, 0, stream>>>(nodein, emb_w1, emb_b1, wT + 0 * 16384, emb_b2, hf);
    for (int l = 0; l < LAYERS; ++l) {
        const unsigned short* wL = wT + (size_t)(2 + 6 * l) * 16384;
        const float* W1 = msg_w1 + (size_t)l * 269 * HF;
        const float* mprev = (l == 0) ? nullptr : msr + (size_t)(l - 1) * 512;
        k_as<<<1152, 256, 0, stream>>>(hf, mprev, wL + 0 * 16384, wL + 1 * 16384,
                                       nodein, W1 + 256 * HF, Abf, Sbf);
        k_aggupd<<<1152, 256, 0, stream>>>(Abf, Sbf, wL + 2 * 16384, msg_b2 + l * HF,
                                           msg_b1 + l * HF, W1 + 268 * HF,
                                           hf, mprev,
                                           wL + 3 * 16384, wL + 4 * 16384,
                                           wL + 5 * 16384, upd_b1 + l * HF,
                                           upd_b2 + l * HF, msr + (size_t)l * 512);
    }
    k_out<<<1152, 256, 0, stream>>>(hf, msr + (size_t)(LAYERS - 1) * 512,
                                    wT + 1 * 16384, out_b1, out_w2, out_b2,
                                    x, (float*)d_out);
}

// Round 13
// 545.737 us; speedup vs baseline: 3.5937x; 3.5937x over previous
//
#include <hip/hip_runtime.h>
#include <math.h>

#define HF 128
#define NB 9216          // nodes per batch (96*96)
#define BB 2
#define MROWS (BB*NB)    // 18432
#define GH 96
#define GW 96
#define LAYERS 6

typedef __attribute__((ext_vector_type(8))) short bf16x8;
typedef __attribute__((ext_vector_type(4))) float f32x4;

#define MFMA16(a, b, c) __builtin_amdgcn_mfma_f32_16x16x32_bf16(a, b, c, 0, 0, 0)

__device__ __forceinline__ float swishf(float x) {
    return __fdividef(x, 1.0f + __expf(-x));
}

// fp32 -> bf16 bits, round-to-nearest-even
__device__ __forceinline__ unsigned short f2b(float f) {
    unsigned u = __float_as_uint(f);
    unsigned r = (u + 0x7fffu + ((u >> 16) & 1u)) >> 16;
    return (unsigned short)r;
}
__device__ __forceinline__ float b2f(unsigned short u) {
    return __uint_as_float((unsigned)u << 16);
}

// normalize 8 hf values -> bf16x8 fragment
__device__ __forceinline__ bf16x8 norm_frag(const float* __restrict__ hp,
                                            const float* __restrict__ mus,
                                            const float* __restrict__ rss, int k0) {
    float4 h0 = *(const float4*)hp;
    float4 h1 = *(const float4*)(hp + 4);
    float4 m0 = *(const float4*)&mus[k0];
    float4 m1 = *(const float4*)&mus[k0 + 4];
    float4 r0 = *(const float4*)&rss[k0];
    float4 r1 = *(const float4*)&rss[k0 + 4];
    union { bf16x8 v; unsigned u[4]; } az;
    float a0 = (h0.x - m0.x) * r0.x, a1 = (h0.y - m0.y) * r0.y;
    az.u[0] = (unsigned)f2b(a0) | ((unsigned)f2b(a1) << 16);
    float a2 = (h0.z - m0.z) * r0.z, a3 = (h0.w - m0.w) * r0.w;
    az.u[1] = (unsigned)f2b(a2) | ((unsigned)f2b(a3) << 16);
    float a4 = (h1.x - m1.x) * r1.x, a5 = (h1.y - m1.y) * r1.y;
    az.u[2] = (unsigned)f2b(a4) | ((unsigned)f2b(a5) << 16);
    float a6 = (h1.z - m1.z) * r1.z, a7 = (h1.w - m1.w) * r1.w;
    az.u[3] = (unsigned)f2b(a6) | ((unsigned)f2b(a7) << 16);
    return az.v;
}

// finalize instance-norm stats in LDS (mraw=nullptr -> identity)
__device__ __forceinline__ void load_musig(const float* __restrict__ mraw, int b, int t,
                                           float* __restrict__ mus, float* __restrict__ rss) {
    if (t < 128) {
        float mu = 0.f, rs = 1.f;
        if (mraw) {
            float s = mraw[b * 128 + t], q = mraw[256 + b * 128 + t];
            mu = s * (1.0f / NB);
            float var = q * (1.0f / NB) - mu * mu;
            rs = rsqrtf(var + 1e-5f);
        }
        mus[t] = mu; rss[t] = rs;
    }
}

// ---------------- weight prep: wT[slot][col][k] = bf16(W[k][col]) ----------------
// slots: 0=emb_w2, 1=out_w1, 2+6l+{0..5} = msgW1a, msgW1b, msgW2, updW1a, updW1b, updW2
__global__ void k_prep(const float* __restrict__ embw2, const float* __restrict__ outw1,
                       const float* __restrict__ msgw1, const float* __restrict__ msgw2,
                       const float* __restrict__ updw1, const float* __restrict__ updw2,
                       unsigned short* __restrict__ wT) {
    int s = blockIdx.x;
    const float* src;
    if (s == 0) src = embw2;
    else if (s == 1) src = outw1;
    else {
        int l = (s - 2) / 6, r = (s - 2) % 6;
        if (r == 0)      src = msgw1 + (size_t)l * 269 * HF;
        else if (r == 1) src = msgw1 + (size_t)l * 269 * HF + HF * HF;
        else if (r == 2) src = msgw2 + (size_t)l * HF * HF;
        else if (r == 3) src = updw1 + (size_t)l * 256 * HF;
        else if (r == 4) src = updw1 + (size_t)l * 256 * HF + HF * HF;
        else             src = updw2 + (size_t)l * HF * HF;
    }
    __shared__ float tile[128][133];
    int t = threadIdx.x;
#pragma unroll
    for (int i = 0; i < 64; ++i) {
        int id = i * 256 + t;
        tile[id >> 7][id & 127] = src[id];
    }
    __syncthreads();
    unsigned short* o = wT + (size_t)s * 16384;
#pragma unroll
    for (int i = 0; i < 64; ++i) {
        int id = i * 256 + t;
        int col = id >> 7, k = id & 127;
        o[id] = f2b(tile[k][col]);
    }
}

// ---------------- build nodein [B,N,16]; zero stat accumulators ----------------
__global__ void k_build(const float* __restrict__ x, const float* __restrict__ pos,
                        float* __restrict__ nodein, float* __restrict__ msr) {
    int idx = blockIdx.x * 256 + threadIdx.x;
    if (idx < LAYERS * 512) msr[idx] = 0.0f;
    if (idx >= MROWS) return;
    int b = idx / NB, n = idx - b * NB;
    float* o = nodein + (size_t)idx * 16;
    const float* xb = x + (size_t)b * 12 * NB + n;
#pragma unroll
    for (int k = 0; k < 12; ++k) o[k] = xb[(size_t)k * NB];
    o[12] = pos[2 * n];
    o[13] = pos[2 * n + 1];
    o[14] = 0.0f; o[15] = 0.0f;
}

// ---------------- fused embedding: t1 = swish(nodein@W1+b1); hf = swish(t1@W2+b2) ----------------
__global__ __launch_bounds__(256, 4)
void k_emb(const float* __restrict__ nodein, const float* __restrict__ w1,
           const float* __restrict__ b1, const unsigned short* __restrict__ wT2,
           const float* __restrict__ b2, float* __restrict__ hf) {
    __shared__ float xs[16][14];
    __shared__ char t1s[4096];
    int t = threadIdx.x;
    int rt = blockIdx.x * 16;
    if (t < 224) {
        int r = t / 14, k = t - r * 14;
        xs[r][k] = nodein[(size_t)(rt + r) * 16 + k];
    }
    __syncthreads();
    {
        int f = t & 127, rblk = t >> 7;
        float wreg[14];
#pragma unroll
        for (int k = 0; k < 14; ++k) wreg[k] = w1[k * HF + f];
        float bv = b1[f];
#pragma unroll
        for (int i = 0; i < 8; ++i) {
            int row = rblk * 8 + i;
            float acc = bv;
#pragma unroll
            for (int k = 0; k < 14; ++k) acc = fmaf(xs[row][k], wreg[k], acc);
            int addr = (row * 256 + f * 2) ^ ((row & 7) << 4);
            *(unsigned short*)(t1s + addr) = f2b(swishf(acc));
        }
    }
    __syncthreads();
    int wave = t >> 6, lane = t & 63, lr = lane & 15, lg = lane >> 4;
    int fb = wave * 32;
    f32x4 acc[2];
    acc[0] = (f32x4)0.0f; acc[1] = (f32x4)0.0f;
#pragma unroll
    for (int kc = 0; kc < 4; ++kc) {
        int k0 = kc * 32 + lg * 8;
        bf16x8 a = *(const bf16x8*)(t1s + ((lr * 256 + k0 * 2) ^ ((lr & 7) << 4)));
#pragma unroll
        for (int j = 0; j < 2; ++j) {
            bf16x8 b = *(const bf16x8*)(wT2 + (size_t)(fb + j * 16 + lr) * HF + k0);
            acc[j] = MFMA16(a, b, acc[j]);
        }
    }
#pragma unroll
    for (int j = 0; j < 2; ++j) {
        int f = fb + j * 16 + lr;
        float bv = b2[f];
#pragma unroll
        for (int r = 0; r < 4; ++r) {
            size_t o = (size_t)(rt + lg * 4 + r) * HF + f;
            hf[o] = swishf(acc[j][r] + bv);
        }
    }
}

// ---------------- A/S projection (norm-on-read) with fused Au ----------------
// A = bf16(norm(hf)@W1a + nodein@W1u) ; S = bf16(norm(hf)@W1b - nodein@W1u)
__global__ __launch_bounds__(256, 4)
void k_as(const float* __restrict__ hf, const float* __restrict__ mraw,
          const unsigned short* __restrict__ wA, const unsigned short* __restrict__ wB,
          const float* __restrict__ nodein, const float* __restrict__ w1u,
          unsigned short* __restrict__ A, unsigned short* __restrict__ S) {
    __shared__ float w1s[12][128];
    __shared__ float nis[16][12];
    __shared__ float mus[128], rss[128];
    int t = threadIdx.x, wave = t >> 6, lane = t & 63, lr = lane & 15, lg = lane >> 4;
    int rt = blockIdx.x * 16;
    int b = blockIdx.x / (NB / 16);
    int fb = wave * 32;
    for (int i = t; i < 12 * 128; i += 256) w1s[i >> 7][i & 127] = w1u[i];
    if (t < 192) {
        int r = t / 12, k = t - (t / 12) * 12;
        nis[r][k] = nodein[(size_t)(rt + r) * 16 + k];
    }
    load_musig(mraw, b, t, mus, rss);
    __syncthreads();
    f32x4 accA[2], accS[2];
    accA[0] = (f32x4)0.0f; accA[1] = (f32x4)0.0f;
    accS[0] = (f32x4)0.0f; accS[1] = (f32x4)0.0f;
#pragma unroll
    for (int kc = 0; kc < 4; ++kc) {
        int k0 = kc * 32 + lg * 8;
        bf16x8 a = norm_frag(hf + (size_t)(rt + lr) * HF + k0, mus, rss, k0);
#pragma unroll
        for (int j = 0; j < 2; ++j) {
            bf16x8 bA = *(const bf16x8*)(wA + (size_t)(fb + j * 16 + lr) * HF + k0);
            accA[j] = MFMA16(a, bA, accA[j]);
            bf16x8 bS = *(const bf16x8*)(wB + (size_t)(fb + j * 16 + lr) * HF + k0);
            accS[j] = MFMA16(a, bS, accS[j]);
        }
    }
#pragma unroll
    for (int j = 0; j < 2; ++j) {
        int f = fb + j * 16 + lr;
        float au[4] = {0.f, 0.f, 0.f, 0.f};
#pragma unroll
        for (int k = 0; k < 12; ++k) {
            float wv = w1s[k][f];
#pragma unroll
            for (int r = 0; r < 4; ++r) au[r] = fmaf(nis[lg * 4 + r][k], wv, au[r]);
        }
#pragma unroll
        for (int r = 0; r < 4; ++r) {
            size_t o = (size_t)(rt + lg * 4 + r) * HF + f;
            A[o] = f2b(accA[j][r] + au[r]);
            S[o] = f2b(accS[j][r] - au[r]);
        }
    }
}

// ---------------- fused message+aggregate+update (3-offset groups, small LDS):
// agg = (1/deg) sum_off swish(swish(A+S+D)@W2m + b2m)
// t1  = swish(norm(hf)@W1a + agg@W1b + b1u)
// v   = swish(t1@W2u + b2u) + norm(hf); hf <- v; stats -> atomicAdd msr ----------------
__global__ __launch_bounds__(256, 4)
void k_aggupd(const unsigned short* __restrict__ Ab, const unsigned short* __restrict__ Sb,
              const unsigned short* __restrict__ wT2, const float* __restrict__ b2m,
              const float* __restrict__ b1m, const float* __restrict__ w1d,
              float* __restrict__ hf, const float* __restrict__ mraw,
              const unsigned short* __restrict__ w1a, const unsigned short* __restrict__ w1b,
              const unsigned short* __restrict__ w2u, const float* __restrict__ b1u,
              const float* __restrict__ b2u, float* __restrict__ msr) {
    __shared__ float dsb[3][128];
    __shared__ float mus[128], rss[128];
    __shared__ char exb[3 * 4096];       // 3-offset z groups; phase3: agg @0, t1 @4096
    int t = threadIdx.x, kq = t >> 6, lane = t & 63, lr = lane & 15, lg = lane >> 4;
    int bx = blockIdx.x;
    int b = bx / (NB / 16), tile = bx % (NB / 16);
    int rt = tile * 16;                  // LOCAL row within batch (16 | 96)
    int fb = kq * 32;
    size_t bN = (size_t)b * NB;
    int R = rt / GW, C0 = rt % GW;
    bool interior = (R > 0) && (R < GH - 1) && (C0 > 0) && (C0 + 16 < GW);

    if (t < 128) {
        float bb = b1m[t], wd = w1d[t];
        dsb[0][t] = bb;
        dsb[1][t] = fmaf(1.0f / 95.0f, wd, bb);
        dsb[2][t] = fmaf(1.4142135623730951f / 95.0f, wd, bb);
    }
    load_musig(mraw, b, t, mus, rss);
    bf16x8 w2f[2][4];
#pragma unroll
    for (int j = 0; j < 2; ++j)
#pragma unroll
        for (int kc = 0; kc < 4; ++kc)
            w2f[j][kc] = *(const bf16x8*)(wT2 + (size_t)(fb + j * 16 + lr) * HF
                                          + kc * 32 + lg * 8);
    int rowA = rt + lr;
    float Af[8];
    {
        bf16x8 av = *(const bf16x8*)(Ab + (bN + rowA) * HF + kq * 32 + lg * 8);
#pragma unroll
        for (int e = 0; e < 8; ++e) Af[e] = b2f((unsigned short)av[e]);
    }
    float b2r[2] = { b2m[fb + lr], b2m[fb + 16 + lr] };
    int lofs = lane * 16;
    __syncthreads();   // dsb/mus ready

    f32x4 agg2[2];
    agg2[0] = (f32x4)0.0f; agg2[1] = (f32x4)0.0f;
    bf16x8 sv;
    {
        int src = rowA - 97;
        if (!interior) src = min(max(src, 0), NB - 1);
        sv = *(const bf16x8*)(Sb + (bN + src) * HF + kq * 32 + lg * 8);
    }
#pragma unroll
    for (int g = 0; g < 3; ++g) {
        // ---- z for offsets 3g..3g+2 (own k-quarter) ----
#pragma unroll
        for (int oi = 0; oi < 3; ++oi) {
            int off = g * 3 + oi;
            int dr = off / 3 - 1, dc = off % 3 - 1;
            int dd = dr * dr + dc * dc;
            bf16x8 cur = sv;
            if (off < 8) {
                int no = off + 1;
                int dnn = (no / 3 - 1) * GW + (no % 3 - 1);
                int src = rowA + dnn;
                if (!interior) src = min(max(src, 0), NB - 1);
                sv = *(const bf16x8*)(Sb + (bN + src) * HF + kq * 32 + lg * 8);
            }
            const float* dp = &dsb[dd][kq * 32 + lg * 8];
            union { bf16x8 v; unsigned u[4]; } cu; cu.v = cur;
            union { bf16x8 v; unsigned u[4]; } az;
#pragma unroll
            for (int q = 0; q < 4; ++q) {
                float sl = __uint_as_float(cu.u[q] << 16);
                float sh = __uint_as_float(cu.u[q] & 0xffff0000u);
                float zl = swishf(Af[2 * q]     + sl + dp[2 * q]);
                float zh = swishf(Af[2 * q + 1] + sh + dp[2 * q + 1]);
                az.u[q] = (unsigned)f2b(zl) | ((unsigned)f2b(zh) << 16);
            }
            *(bf16x8*)(exb + oi * 4096 + kq * 1024 + lofs) = az.v;
        }
        __syncthreads();
        // ---- MFMA + epilogue for offsets 3g..3g+2 ----
#pragma unroll
        for (int oi = 0; oi < 3; ++oi) {
            int off = g * 3 + oi;
            int dr = off / 3 - 1, dc = off % 3 - 1;
            f32x4 acc[2];
            acc[0] = (f32x4)0.0f; acc[1] = (f32x4)0.0f;
#pragma unroll
            for (int kc = 0; kc < 4; ++kc) {
                bf16x8 a = *(const bf16x8*)(exb + oi * 4096 + kc * 1024 + lofs);
                acc[0] = MFMA16(a, w2f[0][kc], acc[0]);
                acc[1] = MFMA16(a, w2f[1][kc], acc[1]);
            }
            if (interior) {
#pragma unroll
                for (int j = 0; j < 2; ++j)
#pragma unroll
                    for (int r = 0; r < 4; ++r)
                        agg2[j][r] += swishf(acc[j][r] + b2r[j]);
            } else {
                bool rOK = (unsigned)(R + dr) < (unsigned)GH;
#pragma unroll
                for (int j = 0; j < 2; ++j)
#pragma unroll
                    for (int r = 0; r < 4; ++r) {
                        int C = C0 + lg * 4 + r;
                        if (rOK && (unsigned)(C + dc) < (unsigned)GW)
                            agg2[j][r] += swishf(acc[j][r] + b2r[j]);
                    }
            }
        }
        __syncthreads();
    }

    // ---- agg tile -> LDS (bf16, swizzled, rows local 0..15) ----
#pragma unroll
    for (int j = 0; j < 2; ++j)
#pragma unroll
        for (int r = 0; r < 4; ++r) {
            int row = lg * 4 + r;
            float v;
            if (interior) {
                v = agg2[j][r] * (1.0f / 9.0f);
            } else {
                float nr = 1.0f + (R > 0) + (R < GH - 1);
                int C = C0 + row;
                float nc = 1.0f + (C > 0) + (C < GW - 1);
                v = __fdividef(agg2[j][r], nr * nc);
            }
            int f = fb + j * 16 + lr;
            int addr = (row * 256 + f * 2) ^ ((row & 7) << 4);
            *(unsigned short*)(exb + addr) = f2b(v);
        }
    __syncthreads();

    // ---- update GEMM1 (norm(hf), agg) — hf rows are GLOBAL (bN + rt) ----
    f32x4 acc[2];
    acc[0] = (f32x4)0.0f; acc[1] = (f32x4)0.0f;
#pragma unroll
    for (int kc = 0; kc < 4; ++kc) {
        int k0 = kc * 32 + lg * 8;
        bf16x8 a1 = norm_frag(hf + (bN + rt + lr) * HF + k0, mus, rss, k0);
        bf16x8 a2 = *(const bf16x8*)(exb + ((lr * 256 + k0 * 2) ^ ((lr & 7) << 4)));
#pragma unroll
        for (int j = 0; j < 2; ++j) {
            bf16x8 bA = *(const bf16x8*)(w1a + (size_t)(fb + j * 16 + lr) * HF + k0);
            acc[j] = MFMA16(a1, bA, acc[j]);
            bf16x8 bB = *(const bf16x8*)(w1b + (size_t)(fb + j * 16 + lr) * HF + k0);
            acc[j] = MFMA16(a2, bB, acc[j]);
        }
    }
    // t1 = swish(acc + b1u) -> swizzled LDS @4096
#pragma unroll
    for (int j = 0; j < 2; ++j) {
        int col = fb + j * 16 + lr;
        float bv = b1u[col];
#pragma unroll
        for (int r = 0; r < 4; ++r) {
            int row = lg * 4 + r;
            int addr = (row * 256 + col * 2) ^ ((row & 7) << 4);
            *(unsigned short*)(exb + 4096 + addr) = f2b(swishf(acc[j][r] + bv));
        }
    }
    __syncthreads();
    // GEMM2
    f32x4 acc2[2];
    acc2[0] = (f32x4)0.0f; acc2[1] = (f32x4)0.0f;
#pragma unroll
    for (int kc = 0; kc < 4; ++kc) {
        int k0 = kc * 32 + lg * 8;
        bf16x8 a = *(const bf16x8*)(exb + 4096 + ((lr * 256 + k0 * 2) ^ ((lr & 7) << 4)));
#pragma unroll
        for (int j = 0; j < 2; ++j) {
            bf16x8 bfr = *(const bf16x8*)(w2u + (size_t)(fb + j * 16 + lr) * HF + k0);
            acc2[j] = MFMA16(a, bfr, acc2[j]);
        }
    }
#pragma unroll
    for (int j = 0; j < 2; ++j) {
        int f = fb + j * 16 + lr;
        float bv = b2u[f];
        float mu = mus[f], rs = rss[f];
        float s1 = 0.f, s2 = 0.f;
#pragma unroll
        for (int r = 0; r < 4; ++r) {
            size_t o = (bN + rt + lg * 4 + r) * HF + f;
            float v = swishf(acc2[j][r] + bv) + (hf[o] - mu) * rs;
            hf[o] = v;
            s1 += v; s2 += v * v;
        }
        s1 += __shfl_xor(s1, 16); s1 += __shfl_xor(s1, 32);
        s2 += __shfl_xor(s2, 16); s2 += __shfl_xor(s2, 32);
        if (lg == 0) {
            atomicAdd(&msr[b * 128 + f], s1);
            atomicAdd(&msr[256 + b * 128 + f], s2);
        }
    }
}

// ---------------- fused output head (norm-on-read):
// g1 = swish(norm(hf)@W1+b1); out = x[:,-1] + g1@W2 + b2 ----------------
__global__ __launch_bounds__(256, 4)
void k_out(const float* __restrict__ hf, const float* __restrict__ mraw,
           const unsigned short* __restrict__ wT1, const float* __restrict__ b1,
           const float* __restrict__ w2, const float* __restrict__ b2,
           const float* __restrict__ x, float* __restrict__ out) {
    __shared__ float g1s[16][132];
    __shared__ float w2s[384];
    __shared__ float mus[128], rss[128];
    int t = threadIdx.x, wave = t >> 6, lane = t & 63, lr = lane & 15, lg = lane >> 4;
    int rt = blockIdx.x * 16;
    int b = blockIdx.x / (NB / 16);
    int fb = wave * 32;
    for (int i = t; i < 384; i += 256) w2s[i] = w2[i];
    load_musig(mraw, b, t, mus, rss);
    __syncthreads();
    f32x4 acc[2];
    acc[0] = (f32x4)0.0f; acc[1] = (f32x4)0.0f;
#pragma unroll
    for (int kc = 0; kc < 4; ++kc) {
        int k0 = kc * 32 + lg * 8;
        bf16x8 a = norm_frag(hf + (size_t)(rt + lr) * HF + k0, mus, rss, k0);
#pragma unroll
        for (int j = 0; j < 2; ++j) {
            bf16x8 bfr = *(const bf16x8*)(wT1 + (size_t)(fb + j * 16 + lr) * HF + k0);
            acc[j] = MFMA16(a, bfr, acc[j]);
        }
    }
#pragma unroll
    for (int j = 0; j < 2; ++j) {
        int f = fb + j * 16 + lr;
        float bv = b1[f];
#pragma unroll
        for (int r = 0; r < 4; ++r)
            g1s[lg * 4 + r][f] = swishf(acc[j][r] + bv);
    }
    __syncthreads();
    if (t < 48) {
        int r = t / 3, c = t - (t / 3) * 3;
        int row = rt + r;
        int bb = row / NB, n = row - bb * NB;
        float a = b2[c];
#pragma unroll 8
        for (int k = 0; k < HF; ++k) a = fmaf(g1s[r][k], w2s[k * 3 + c], a);
        float xv = x[(((size_t)bb * 4 + 3) * 3 + c) * NB + n];
        out[((size_t)bb * 3 + c) * NB + n] = a + xv;
    }
}

extern "C" void kernel_launch(void* const* d_in, const int* in_sizes, int n_in,
                              void* d_out, int out_size, void* d_ws, size_t ws_size,
                              hipStream_t stream) {
    const float* x      = (const float*)d_in[0];
    const float* pos    = (const float*)d_in[3];
    const float* emb_w1 = (const float*)d_in[4];
    const float* emb_b1 = (const float*)d_in[5];
    const float* emb_b2 = (const float*)d_in[7];
    const float* msg_w1 = (const float*)d_in[8];
    const float* msg_b1 = (const float*)d_in[9];
    const float* msg_b2 = (const float*)d_in[11];
    const float* upd_b1 = (const float*)d_in[13];
    const float* upd_b2 = (const float*)d_in[15];
    const float* out_b1 = (const float*)d_in[17];
    const float* out_w2 = (const float*)d_in[18];
    const float* out_b2 = (const float*)d_in[19];

    float* w = (float*)d_ws;
    size_t off = 0;
    auto alloc = [&](size_t n) { float* p = w + off; off += n; return p; };
    float* nodein  = alloc((size_t)MROWS * 16);
    float* hf      = alloc((size_t)MROWS * HF);
    float* msr     = alloc((size_t)LAYERS * 512);   // per-layer [sum|sumsq] accumulators
    unsigned short* Abf  = (unsigned short*)alloc((size_t)MROWS * 64);
    unsigned short* Sbf  = (unsigned short*)alloc((size_t)MROWS * 64);
    unsigned short* wT   = (unsigned short*)alloc((size_t)38 * 16384 / 2);
    (void)ws_size; (void)in_sizes; (void)n_in; (void)out_size;

    k_prep<<<38, 256, 0, stream>>>((const float*)d_in[6], (const float*)d_in[16],
                                   msg_w1, (const float*)d_in[10],
                                   (const float*)d_in[12], (const float*)d_in[14], wT);
    k_build<<<(MROWS + 255) / 256, 256, 0, stream>>>(x, pos, nodein, msr);
    k_emb<<<1152, 256, 0, stream>>>(nodein, emb_w1, emb_b1, wT + 0 * 16384, emb_b2, hf);
    for (int l = 0; l < LAYERS; ++l) {
        const unsigned short* wL = wT + (size_t)(2 + 6 * l) * 16384;
        const float* W1 = msg_w1 + (size_t)l * 269 * HF;
        const float* mprev = (l == 0) ? nullptr : msr + (size_t)(l - 1) * 512;
        k_as<<<1152, 256, 0, stream>>>(hf, mprev, wL + 0 * 16384, wL + 1 * 16384,
                                       nodein, W1 + 256 * HF, Abf, Sbf);
        k_aggupd<<<1152, 256, 0, stream>>>(Abf, Sbf, wL + 2 * 16384, msg_b2 + l * HF,
                                           msg_b1 + l * HF, W1 + 268 * HF,
                                           hf, mprev,
                                           wL + 3 * 16384, wL + 4 * 16384,
                                           wL + 5 * 16384, upd_b1 + l * HF,
                                           upd_b2 + l * HF, msr + (size_t)l * 512);
    }
    k_out<<<1152, 256, 0, stream>>>(hf, msr + (size_t)(LAYERS - 1) * 512,
                                    wT + 1 * 16384, out_b1, out_w2, out_b2,
                                    x, (float*)d_out);
}

// Round 14
// 462.441 us; speedup vs baseline: 4.2410x; 1.1801x over previous
//
#include <hip/hip_runtime.h>
#include <math.h>

#define HF 128
#define NB 9216          // nodes per batch (96*96)
#define BB 2
#define MROWS (BB*NB)    // 18432
#define GH 96
#define GW 96
#define LAYERS 6

typedef __attribute__((ext_vector_type(8))) short bf16x8;
typedef __attribute__((ext_vector_type(4))) float f32x4;

#define MFMA16(a, b, c) __builtin_amdgcn_mfma_f32_16x16x32_bf16(a, b, c, 0, 0, 0)

__device__ __forceinline__ float swishf(float x) {
    return __fdividef(x, 1.0f + __expf(-x));
}

// fp32 -> bf16 bits, round-to-nearest-even
__device__ __forceinline__ unsigned short f2b(float f) {
    unsigned u = __float_as_uint(f);
    unsigned r = (u + 0x7fffu + ((u >> 16) & 1u)) >> 16;
    return (unsigned short)r;
}
__device__ __forceinline__ float b2f(unsigned short u) {
    return __uint_as_float((unsigned)u << 16);
}

// normalize 8 hf values -> bf16x8 fragment
__device__ __forceinline__ bf16x8 norm_frag(const float* __restrict__ hp,
                                            const float* __restrict__ mus,
                                            const float* __restrict__ rss, int k0) {
    float4 h0 = *(const float4*)hp;
    float4 h1 = *(const float4*)(hp + 4);
    float4 m0 = *(const float4*)&mus[k0];
    float4 m1 = *(const float4*)&mus[k0 + 4];
    float4 r0 = *(const float4*)&rss[k0];
    float4 r1 = *(const float4*)&rss[k0 + 4];
    union { bf16x8 v; unsigned u[4]; } az;
    float a0 = (h0.x - m0.x) * r0.x, a1 = (h0.y - m0.y) * r0.y;
    az.u[0] = (unsigned)f2b(a0) | ((unsigned)f2b(a1) << 16);
    float a2 = (h0.z - m0.z) * r0.z, a3 = (h0.w - m0.w) * r0.w;
    az.u[1] = (unsigned)f2b(a2) | ((unsigned)f2b(a3) << 16);
    float a4 = (h1.x - m1.x) * r1.x, a5 = (h1.y - m1.y) * r1.y;
    az.u[2] = (unsigned)f2b(a4) | ((unsigned)f2b(a5) << 16);
    float a6 = (h1.z - m1.z) * r1.z, a7 = (h1.w - m1.w) * r1.w;
    az.u[3] = (unsigned)f2b(a6) | ((unsigned)f2b(a7) << 16);
    return az.v;
}

// finalize instance-norm stats in LDS (mraw=nullptr -> identity)
__device__ __forceinline__ void load_musig(const float* __restrict__ mraw, int b, int t,
                                           float* __restrict__ mus, float* __restrict__ rss) {
    if (t < 128) {
        float mu = 0.f, rs = 1.f;
        if (mraw) {
            float s = mraw[b * 128 + t], q = mraw[256 + b * 128 + t];
            mu = s * (1.0f / NB);
            float var = q * (1.0f / NB) - mu * mu;
            rs = rsqrtf(var + 1e-5f);
        }
        mus[t] = mu; rss[t] = rs;
    }
}

// ---------------- weight prep: wT[slot][col][k] = bf16(W[k][col]) ----------------
// slots: 0=emb_w2, 1=out_w1, 2+6l+{0..5} = msgW1a, msgW1b, msgW2, updW1a, updW1b, updW2
__global__ void k_prep(const float* __restrict__ embw2, const float* __restrict__ outw1,
                       const float* __restrict__ msgw1, const float* __restrict__ msgw2,
                       const float* __restrict__ updw1, const float* __restrict__ updw2,
                       unsigned short* __restrict__ wT) {
    int s = blockIdx.x;
    const float* src;
    if (s == 0) src = embw2;
    else if (s == 1) src = outw1;
    else {
        int l = (s - 2) / 6, r = (s - 2) % 6;
        if (r == 0)      src = msgw1 + (size_t)l * 269 * HF;
        else if (r == 1) src = msgw1 + (size_t)l * 269 * HF + HF * HF;
        else if (r == 2) src = msgw2 + (size_t)l * HF * HF;
        else if (r == 3) src = updw1 + (size_t)l * 256 * HF;
        else if (r == 4) src = updw1 + (size_t)l * 256 * HF + HF * HF;
        else             src = updw2 + (size_t)l * HF * HF;
    }
    __shared__ float tile[128][133];
    int t = threadIdx.x;
#pragma unroll
    for (int i = 0; i < 64; ++i) {
        int id = i * 256 + t;
        tile[id >> 7][id & 127] = src[id];
    }
    __syncthreads();
    unsigned short* o = wT + (size_t)s * 16384;
#pragma unroll
    for (int i = 0; i < 64; ++i) {
        int id = i * 256 + t;
        int col = id >> 7, k = id & 127;
        o[id] = f2b(tile[k][col]);
    }
}

// ---------------- build nodein [B,N,16]; zero stat accumulators ----------------
__global__ void k_build(const float* __restrict__ x, const float* __restrict__ pos,
                        float* __restrict__ nodein, float* __restrict__ msr) {
    int idx = blockIdx.x * 256 + threadIdx.x;
    if (idx < LAYERS * 512) msr[idx] = 0.0f;
    if (idx >= MROWS) return;
    int b = idx / NB, n = idx - b * NB;
    float* o = nodein + (size_t)idx * 16;
    const float* xb = x + (size_t)b * 12 * NB + n;
#pragma unroll
    for (int k = 0; k < 12; ++k) o[k] = xb[(size_t)k * NB];
    o[12] = pos[2 * n];
    o[13] = pos[2 * n + 1];
    o[14] = 0.0f; o[15] = 0.0f;
}

// ---------------- fused embedding: t1 = swish(nodein@W1+b1); hf = swish(t1@W2+b2) ----------------
__global__ __launch_bounds__(256, 4)
void k_emb(const float* __restrict__ nodein, const float* __restrict__ w1,
           const float* __restrict__ b1, const unsigned short* __restrict__ wT2,
           const float* __restrict__ b2, float* __restrict__ hf) {
    __shared__ float xs[16][14];
    __shared__ char t1s[4096];
    int t = threadIdx.x;
    int rt = blockIdx.x * 16;
    if (t < 224) {
        int r = t / 14, k = t - r * 14;
        xs[r][k] = nodein[(size_t)(rt + r) * 16 + k];
    }
    __syncthreads();
    {
        int f = t & 127, rblk = t >> 7;
        float wreg[14];
#pragma unroll
        for (int k = 0; k < 14; ++k) wreg[k] = w1[k * HF + f];
        float bv = b1[f];
#pragma unroll
        for (int i = 0; i < 8; ++i) {
            int row = rblk * 8 + i;
            float acc = bv;
#pragma unroll
            for (int k = 0; k < 14; ++k) acc = fmaf(xs[row][k], wreg[k], acc);
            int addr = (row * 256 + f * 2) ^ ((row & 7) << 4);
            *(unsigned short*)(t1s + addr) = f2b(swishf(acc));
        }
    }
    __syncthreads();
    int wave = t >> 6, lane = t & 63, lr = lane & 15, lg = lane >> 4;
    int fb = wave * 32;
    f32x4 acc[2];
    acc[0] = (f32x4)0.0f; acc[1] = (f32x4)0.0f;
#pragma unroll
    for (int kc = 0; kc < 4; ++kc) {
        int k0 = kc * 32 + lg * 8;
        bf16x8 a = *(const bf16x8*)(t1s + ((lr * 256 + k0 * 2) ^ ((lr & 7) << 4)));
#pragma unroll
        for (int j = 0; j < 2; ++j) {
            bf16x8 b = *(const bf16x8*)(wT2 + (size_t)(fb + j * 16 + lr) * HF + k0);
            acc[j] = MFMA16(a, b, acc[j]);
        }
    }
#pragma unroll
    for (int j = 0; j < 2; ++j) {
        int f = fb + j * 16 + lr;
        float bv = b2[f];
#pragma unroll
        for (int r = 0; r < 4; ++r) {
            size_t o = (size_t)(rt + lg * 4 + r) * HF + f;
            hf[o] = swishf(acc[j][r] + bv);
        }
    }
}

// ---------------- A/S projection (norm-on-read) with fused Au ----------------
// A = bf16(norm(hf)@W1a + nodein@W1u) ; S = bf16(norm(hf)@W1b - nodein@W1u)
__global__ __launch_bounds__(256, 4)
void k_as(const float* __restrict__ hf, const float* __restrict__ mraw,
          const unsigned short* __restrict__ wA, const unsigned short* __restrict__ wB,
          const float* __restrict__ nodein, const float* __restrict__ w1u,
          unsigned short* __restrict__ A, unsigned short* __restrict__ S) {
    __shared__ float w1s[12][128];
    __shared__ float nis[16][12];
    __shared__ float mus[128], rss[128];
    int t = threadIdx.x, wave = t >> 6, lane = t & 63, lr = lane & 15, lg = lane >> 4;
    int rt = blockIdx.x * 16;
    int b = blockIdx.x / (NB / 16);
    int fb = wave * 32;
    for (int i = t; i < 12 * 128; i += 256) w1s[i >> 7][i & 127] = w1u[i];
    if (t < 192) {
        int r = t / 12, k = t - (t / 12) * 12;
        nis[r][k] = nodein[(size_t)(rt + r) * 16 + k];
    }
    load_musig(mraw, b, t, mus, rss);
    __syncthreads();
    f32x4 accA[2], accS[2];
    accA[0] = (f32x4)0.0f; accA[1] = (f32x4)0.0f;
    accS[0] = (f32x4)0.0f; accS[1] = (f32x4)0.0f;
#pragma unroll
    for (int kc = 0; kc < 4; ++kc) {
        int k0 = kc * 32 + lg * 8;
        bf16x8 a = norm_frag(hf + (size_t)(rt + lr) * HF + k0, mus, rss, k0);
#pragma unroll
        for (int j = 0; j < 2; ++j) {
            bf16x8 bA = *(const bf16x8*)(wA + (size_t)(fb + j * 16 + lr) * HF + k0);
            accA[j] = MFMA16(a, bA, accA[j]);
            bf16x8 bS = *(const bf16x8*)(wB + (size_t)(fb + j * 16 + lr) * HF + k0);
            accS[j] = MFMA16(a, bS, accS[j]);
        }
    }
#pragma unroll
    for (int j = 0; j < 2; ++j) {
        int f = fb + j * 16 + lr;
        float au[4] = {0.f, 0.f, 0.f, 0.f};
#pragma unroll
        for (int k = 0; k < 12; ++k) {
            float wv = w1s[k][f];
#pragma unroll
            for (int r = 0; r < 4; ++r) au[r] = fmaf(nis[lg * 4 + r][k], wv, au[r]);
        }
#pragma unroll
        for (int r = 0; r < 4; ++r) {
            size_t o = (size_t)(rt + lg * 4 + r) * HF + f;
            A[o] = f2b(accA[j][r] + au[r]);
            S[o] = f2b(accS[j][r] - au[r]);
        }
    }
}

// ---------------- fused message+aggregate+update (3-offset groups, small LDS,
// single masked path, compact rolled group loop):
// agg = (1/deg) sum_off swish(swish(A+S+D)@W2m + b2m)
// t1  = swish(norm(hf)@W1a + agg@W1b + b1u)
// v   = swish(t1@W2u + b2u) + norm(hf); hf <- v; stats -> atomicAdd msr ----------------
__global__ __launch_bounds__(256, 4)
void k_aggupd(const unsigned short* __restrict__ Ab, const unsigned short* __restrict__ Sb,
              const unsigned short* __restrict__ wT2, const float* __restrict__ b2m,
              const float* __restrict__ b1m, const float* __restrict__ w1d,
              float* __restrict__ hf, const float* __restrict__ mraw,
              const unsigned short* __restrict__ w1a, const unsigned short* __restrict__ w1b,
              const unsigned short* __restrict__ w2u, const float* __restrict__ b1u,
              const float* __restrict__ b2u, float* __restrict__ msr) {
    __shared__ float dsb[3][128];
    __shared__ float mus[128], rss[128];
    __shared__ char exb[3 * 4096];       // 3-offset z groups; phase3: agg @0, t1 @4096
    int t = threadIdx.x, kq = t >> 6, lane = t & 63, lr = lane & 15, lg = lane >> 4;
    int bx = blockIdx.x;
    int b = bx / (NB / 16), tile = bx % (NB / 16);
    int rt = tile * 16;                  // LOCAL row within batch (16 | 96)
    int fb = kq * 32;
    size_t bN = (size_t)b * NB;
    int R = rt / GW, C0 = rt % GW;

    if (t < 128) {
        float bb = b1m[t], wd = w1d[t];
        dsb[0][t] = bb;
        dsb[1][t] = fmaf(1.0f / 95.0f, wd, bb);
        dsb[2][t] = fmaf(1.4142135623730951f / 95.0f, wd, bb);
    }
    load_musig(mraw, b, t, mus, rss);
    bf16x8 w2f[2][4];
#pragma unroll
    for (int j = 0; j < 2; ++j)
#pragma unroll
        for (int kc = 0; kc < 4; ++kc)
            w2f[j][kc] = *(const bf16x8*)(wT2 + (size_t)(fb + j * 16 + lr) * HF
                                          + kc * 32 + lg * 8);
    int rowA = rt + lr;
    float Af[8];
    {
        bf16x8 av = *(const bf16x8*)(Ab + (bN + rowA) * HF + kq * 32 + lg * 8);
#pragma unroll
        for (int e = 0; e < 8; ++e) Af[e] = b2f((unsigned short)av[e]);
    }
    float b2r[2] = { b2m[fb + lr], b2m[fb + 16 + lr] };
    int lofs = lane * 16;
    __syncthreads();   // dsb/mus ready

    f32x4 agg2[2];
    agg2[0] = (f32x4)0.0f; agg2[1] = (f32x4)0.0f;
    bf16x8 sv;
    {
        int src = min(max(rowA - 97, 0), NB - 1);
        sv = *(const bf16x8*)(Sb + (bN + src) * HF + kq * 32 + lg * 8);
    }
#pragma unroll 1
    for (int g = 0; g < 3; ++g) {
        int dr = g - 1;                    // offsets g*3..g*3+2 share dr
        bool rOK = (unsigned)(R + dr) < (unsigned)GH;
        // ---- z for offsets 3g..3g+2 (own k-quarter) ----
#pragma unroll
        for (int oi = 0; oi < 3; ++oi) {
            int off = g * 3 + oi;
            int dc = oi - 1;
            int dd = dr * dr + dc * dc;
            bf16x8 cur = sv;
            if (off < 8) {
                int no = off + 1;
                int dnn = (no / 3 - 1) * GW + (no % 3 - 1);
                int src = min(max(rowA + dnn, 0), NB - 1);
                sv = *(const bf16x8*)(Sb + (bN + src) * HF + kq * 32 + lg * 8);
            }
            const float* dp = &dsb[dd][kq * 32 + lg * 8];
            union { bf16x8 v; unsigned u[4]; } cu; cu.v = cur;
            union { bf16x8 v; unsigned u[4]; } az;
#pragma unroll
            for (int q = 0; q < 4; ++q) {
                float sl = __uint_as_float(cu.u[q] << 16);
                float sh = __uint_as_float(cu.u[q] & 0xffff0000u);
                float zl = swishf(Af[2 * q]     + sl + dp[2 * q]);
                float zh = swishf(Af[2 * q + 1] + sh + dp[2 * q + 1]);
                az.u[q] = (unsigned)f2b(zl) | ((unsigned)f2b(zh) << 16);
            }
            *(bf16x8*)(exb + oi * 4096 + kq * 1024 + lofs) = az.v;
        }
        __syncthreads();
        // ---- MFMA + masked epilogue for offsets 3g..3g+2 ----
#pragma unroll
        for (int oi = 0; oi < 3; ++oi) {
            int dc = oi - 1;
            f32x4 acc[2];
            acc[0] = (f32x4)0.0f; acc[1] = (f32x4)0.0f;
#pragma unroll
            for (int kc = 0; kc < 4; ++kc) {
                bf16x8 a = *(const bf16x8*)(exb + oi * 4096 + kc * 1024 + lofs);
                acc[0] = MFMA16(a, w2f[0][kc], acc[0]);
                acc[1] = MFMA16(a, w2f[1][kc], acc[1]);
            }
#pragma unroll
            for (int j = 0; j < 2; ++j)
#pragma unroll
                for (int r = 0; r < 4; ++r) {
                    int C = C0 + lg * 4 + r;
                    if (rOK && (unsigned)(C + dc) < (unsigned)GW)
                        agg2[j][r] += swishf(acc[j][r] + b2r[j]);
                }
        }
        __syncthreads();
    }

    // ---- agg tile -> LDS (bf16, swizzled, rows local 0..15) ----
    float nr = 1.0f + (R > 0) + (R < GH - 1);
#pragma unroll
    for (int j = 0; j < 2; ++j)
#pragma unroll
        for (int r = 0; r < 4; ++r) {
            int row = lg * 4 + r;
            int C = C0 + row;
            float nc = 1.0f + (C > 0) + (C < GW - 1);
            float v = __fdividef(agg2[j][r], nr * nc);
            int f = fb + j * 16 + lr;
            int addr = (row * 256 + f * 2) ^ ((row & 7) << 4);
            *(unsigned short*)(exb + addr) = f2b(v);
        }
    __syncthreads();

    // ---- update GEMM1 (norm(hf), agg) — hf rows are GLOBAL (bN + rt) ----
    f32x4 acc[2];
    acc[0] = (f32x4)0.0f; acc[1] = (f32x4)0.0f;
#pragma unroll
    for (int kc = 0; kc < 4; ++kc) {
        int k0 = kc * 32 + lg * 8;
        bf16x8 a1 = norm_frag(hf + (bN + rt + lr) * HF + k0, mus, rss, k0);
        bf16x8 a2 = *(const bf16x8*)(exb + ((lr * 256 + k0 * 2) ^ ((lr & 7) << 4)));
#pragma unroll
        for (int j = 0; j < 2; ++j) {
            bf16x8 bA = *(const bf16x8*)(w1a + (size_t)(fb + j * 16 + lr) * HF + k0);
            acc[j] = MFMA16(a1, bA, acc[j]);
            bf16x8 bB = *(const bf16x8*)(w1b + (size_t)(fb + j * 16 + lr) * HF + k0);
            acc[j] = MFMA16(a2, bB, acc[j]);
        }
    }
    // t1 = swish(acc + b1u) -> swizzled LDS @4096
#pragma unroll
    for (int j = 0; j < 2; ++j) {
        int col = fb + j * 16 + lr;
        float bv = b1u[col];
#pragma unroll
        for (int r = 0; r < 4; ++r) {
            int row = lg * 4 + r;
            int addr = (row * 256 + col * 2) ^ ((row & 7) << 4);
            *(unsigned short*)(exb + 4096 + addr) = f2b(swishf(acc[j][r] + bv));
        }
    }
    __syncthreads();
    // GEMM2
    f32x4 acc2[2];
    acc2[0] = (f32x4)0.0f; acc2[1] = (f32x4)0.0f;
#pragma unroll
    for (int kc = 0; kc < 4; ++kc) {
        int k0 = kc * 32 + lg * 8;
        bf16x8 a = *(const bf16x8*)(exb + 4096 + ((lr * 256 + k0 * 2) ^ ((lr & 7) << 4)));
#pragma unroll
        for (int j = 0; j < 2; ++j) {
            bf16x8 bfr = *(const bf16x8*)(w2u + (size_t)(fb + j * 16 + lr) * HF + k0);
            acc2[j] = MFMA16(a, bfr, acc2[j]);
        }
    }
#pragma unroll
    for (int j = 0; j < 2; ++j) {
        int f = fb + j * 16 + lr;
        float bv = b2u[f];
        float mu = mus[f], rs = rss[f];
        float s1 = 0.f, s2 = 0.f;
#pragma unroll
        for (int r = 0; r < 4; ++r) {
            size_t o = (bN + rt + lg * 4 + r) * HF + f;
            float v = swishf(acc2[j][r] + bv) + (hf[o] - mu) * rs;
            hf[o] = v;
            s1 += v; s2 += v * v;
        }
        s1 += __shfl_xor(s1, 16); s1 += __shfl_xor(s1, 32);
        s2 += __shfl_xor(s2, 16); s2 += __shfl_xor(s2, 32);
        if (lg == 0) {
            atomicAdd(&msr[b * 128 + f], s1);
            atomicAdd(&msr[256 + b * 128 + f], s2);
        }
    }
}

// ---------------- fused output head (norm-on-read):
// g1 = swish(norm(hf)@W1+b1); out = x[:,-1] + g1@W2 + b2 ----------------
__global__ __launch_bounds__(256, 4)
void k_out(const float* __restrict__ hf, const float* __restrict__ mraw,
           const unsigned short* __restrict__ wT1, const float* __restrict__ b1,
           const float* __restrict__ w2, const float* __restrict__ b2,
           const float* __restrict__ x, float* __restrict__ out) {
    __shared__ float g1s[16][132];
    __shared__ float w2s[384];
    __shared__ float mus[128], rss[128];
    int t = threadIdx.x, wave = t >> 6, lane = t & 63, lr = lane & 15, lg = lane >> 4;
    int rt = blockIdx.x * 16;
    int b = blockIdx.x / (NB / 16);
    int fb = wave * 32;
    for (int i = t; i < 384; i += 256) w2s[i] = w2[i];
    load_musig(mraw, b, t, mus, rss);
    __syncthreads();
    f32x4 acc[2];
    acc[0] = (f32x4)0.0f; acc[1] = (f32x4)0.0f;
#pragma unroll
    for (int kc = 0; kc < 4; ++kc) {
        int k0 = kc * 32 + lg * 8;
        bf16x8 a = norm_frag(hf + (size_t)(rt + lr) * HF + k0, mus, rss, k0);
#pragma unroll
        for (int j = 0; j < 2; ++j) {
            bf16x8 bfr = *(const bf16x8*)(wT1 + (size_t)(fb + j * 16 + lr) * HF + k0);
            acc[j] = MFMA16(a, bfr, acc[j]);
        }
    }
#pragma unroll
    for (int j = 0; j < 2; ++j) {
        int f = fb + j * 16 + lr;
        float bv = b1[f];
#pragma unroll
        for (int r = 0; r < 4; ++r)
            g1s[lg * 4 + r][f] = swishf(acc[j][r] + bv);
    }
    __syncthreads();
    if (t < 48) {
        int r = t / 3, c = t - (t / 3) * 3;
        int row = rt + r;
        int bb = row / NB, n = row - bb * NB;
        float a = b2[c];
#pragma unroll 8
        for (int k = 0; k < HF; ++k) a = fmaf(g1s[r][k], w2s[k * 3 + c], a);
        float xv = x[(((size_t)bb * 4 + 3) * 3 + c) * NB + n];
        out[((size_t)bb * 3 + c) * NB + n] = a + xv;
    }
}

extern "C" void kernel_launch(void* const* d_in, const int* in_sizes, int n_in,
                              void* d_out, int out_size, void* d_ws, size_t ws_size,
                              hipStream_t stream) {
    const float* x      = (const float*)d_in[0];
    const float* pos    = (const float*)d_in[3];
    const float* emb_w1 = (const float*)d_in[4];
    const float* emb_b1 = (const float*)d_in[5];
    const float* emb_b2 = (const float*)d_in[7];
    const float* msg_w1 = (const float*)d_in[8];
    const float* msg_b1 = (const float*)d_in[9];
    const float* msg_b2 = (const float*)d_in[11];
    const float* upd_b1 = (const float*)d_in[13];
    const float* upd_b2 = (const float*)d_in[15];
    const float* out_b1 = (const float*)d_in[17];
    const float* out_w2 = (const float*)d_in[18];
    const float* out_b2 = (const float*)d_in[19];

    float* w = (float*)d_ws;
    size_t off = 0;
    auto alloc = [&](size_t n) { float* p = w + off; off += n; return p; };
    float* nodein  = alloc((size_t)MROWS * 16);
    float* hf      = alloc((size_t)MROWS * HF);
    float* msr     = alloc((size_t)LAYERS * 512);   // per-layer [sum|sumsq] accumulators
    unsigned short* Abf  = (unsigned short*)alloc((size_t)MROWS * 64);
    unsigned short* Sbf  = (unsigned short*)alloc((size_t)MROWS * 64);
    unsigned short* wT   = (unsigned short*)alloc((size_t)38 * 16384 / 2);
    (void)ws_size; (void)in_sizes; (void)n_in; (void)out_size;

    k_prep<<<38, 256, 0, stream>>>((const float*)d_in[6], (const float*)d_in[16],
                                   msg_w1, (const float*)d_in[10],
                                   (const float*)d_in[12], (const float*)d_in[14], wT);
    k_build<<<(MROWS + 255) / 256, 256, 0, stream>>>(x, pos, nodein, msr);
    k_emb<<<1152, 256, 0, stream>>>(nodein, emb_w1, emb_b1, wT + 0 * 16384, emb_b2, hf);
    for (int l = 0; l < LAYERS; ++l) {
        const unsigned short* wL = wT + (size_t)(2 + 6 * l) * 16384;
        const float* W1 = msg_w1 + (size_t)l * 269 * HF;
        const float* mprev = (l == 0) ? nullptr : msr + (size_t)(l - 1) * 512;
        k_as<<<1152, 256, 0, stream>>>(hf, mprev, wL + 0 * 16384, wL + 1 * 16384,
                                       nodein, W1 + 256 * HF, Abf, Sbf);
        k_aggupd<<<1152, 256, 0, stream>>>(Abf, Sbf, wL + 2 * 16384, msg_b2 + l * HF,
                                           msg_b1 + l * HF, W1 + 268 * HF,
                                           hf, mprev,
                                           wL + 3 * 16384, wL + 4 * 16384,
                                           wL + 5 * 16384, upd_b1 + l * HF,
                                           upd_b2 + l * HF, msr + (size_t)l * 512);
    }
    k_out<<<1152, 256, 0, stream>>>(hf, msr + (size_t)(LAYERS - 1) * 512,
                                    wT + 1 * 16384, out_b1, out_w2, out_b2,
                                    x, (float*)d_out);
}

// Round 16
// 456.612 us; speedup vs baseline: 4.2951x; 1.0128x over previous
//
#include <hip/hip_runtime.h>
#include <hip/hip_bf16.h>
#include <math.h>

#define HF 128
#define NB 9216          // nodes per batch (96*96)
#define BB 2
#define MROWS (BB*NB)    // 18432
#define GH 96
#define GW 96
#define LAYERS 6

typedef __attribute__((ext_vector_type(8))) short bf16x8;
typedef __attribute__((ext_vector_type(4))) float f32x4;

#define MFMA16(a, b, c) __builtin_amdgcn_mfma_f32_16x16x32_bf16(a, b, c, 0, 0, 0)

__device__ __forceinline__ float swishf(float x) {
    return __fdividef(x, 1.0f + __expf(-x));
}

// fp32 -> bf16 bits via native cvt (RNE)
__device__ __forceinline__ unsigned short f2b(float f) {
    __hip_bfloat16 h = __float2bfloat16(f);
    return *reinterpret_cast<unsigned short*>(&h);
}
// pack two fp32 -> packed 2xbf16 (RNE); compiler-fusible to v_cvt_pk_bf16_f32
__device__ __forceinline__ unsigned pk2(float lo, float hi) {
    return (unsigned)f2b(lo) | ((unsigned)f2b(hi) << 16);
}
__device__ __forceinline__ float b2f(unsigned short u) {
    return __uint_as_float((unsigned)u << 16);
}

// normalize 8 hf values -> bf16x8 fragment
__device__ __forceinline__ bf16x8 norm_frag(const float* __restrict__ hp,
                                            const float* __restrict__ mus,
                                            const float* __restrict__ rss, int k0) {
    float4 h0 = *(const float4*)hp;
    float4 h1 = *(const float4*)(hp + 4);
    float4 m0 = *(const float4*)&mus[k0];
    float4 m1 = *(const float4*)&mus[k0 + 4];
    float4 r0 = *(const float4*)&rss[k0];
    float4 r1 = *(const float4*)&rss[k0 + 4];
    union { bf16x8 v; unsigned u[4]; } az;
    az.u[0] = pk2((h0.x - m0.x) * r0.x, (h0.y - m0.y) * r0.y);
    az.u[1] = pk2((h0.z - m0.z) * r0.z, (h0.w - m0.w) * r0.w);
    az.u[2] = pk2((h1.x - m1.x) * r1.x, (h1.y - m1.y) * r1.y);
    az.u[3] = pk2((h1.z - m1.z) * r1.z, (h1.w - m1.w) * r1.w);
    return az.v;
}

// finalize instance-norm stats in LDS (mraw=nullptr -> identity)
__device__ __forceinline__ void load_musig(const float* __restrict__ mraw, int b, int t,
                                           float* __restrict__ mus, float* __restrict__ rss) {
    if (t < 128) {
        float mu = 0.f, rs = 1.f;
        if (mraw) {
            float s = mraw[b * 128 + t], q = mraw[256 + b * 128 + t];
            mu = s * (1.0f / NB);
            float var = q * (1.0f / NB) - mu * mu;
            rs = rsqrtf(var + 1e-5f);
        }
        mus[t] = mu; rss[t] = rs;
    }
}

// ---------------- weight prep: wT[slot][col][k] = bf16(W[k][col]) ----------------
// slots: 0=emb_w2, 1=out_w1, 2+6l+{0..5} = msgW1a, msgW1b, msgW2, updW1a, updW1b, updW2
__global__ void k_prep(const float* __restrict__ embw2, const float* __restrict__ outw1,
                       const float* __restrict__ msgw1, const float* __restrict__ msgw2,
                       const float* __restrict__ updw1, const float* __restrict__ updw2,
                       unsigned short* __restrict__ wT) {
    int s = blockIdx.x;
    const float* src;
    if (s == 0) src = embw2;
    else if (s == 1) src = outw1;
    else {
        int l = (s - 2) / 6, r = (s - 2) % 6;
        if (r == 0)      src = msgw1 + (size_t)l * 269 * HF;
        else if (r == 1) src = msgw1 + (size_t)l * 269 * HF + HF * HF;
        else if (r == 2) src = msgw2 + (size_t)l * HF * HF;
        else if (r == 3) src = updw1 + (size_t)l * 256 * HF;
        else if (r == 4) src = updw1 + (size_t)l * 256 * HF + HF * HF;
        else             src = updw2 + (size_t)l * HF * HF;
    }
    __shared__ float tile[128][133];
    int t = threadIdx.x;
#pragma unroll
    for (int i = 0; i < 64; ++i) {
        int id = i * 256 + t;
        tile[id >> 7][id & 127] = src[id];
    }
    __syncthreads();
    unsigned short* o = wT + (size_t)s * 16384;
#pragma unroll
    for (int i = 0; i < 64; ++i) {
        int id = i * 256 + t;
        int col = id >> 7, k = id & 127;
        o[id] = f2b(tile[k][col]);
    }
}

// ---------------- build nodein [B,N,16]; zero stat accumulators ----------------
__global__ void k_build(const float* __restrict__ x, const float* __restrict__ pos,
                        float* __restrict__ nodein, float* __restrict__ msr) {
    int idx = blockIdx.x * 256 + threadIdx.x;
    if (idx < LAYERS * 512) msr[idx] = 0.0f;
    if (idx >= MROWS) return;
    int b = idx / NB, n = idx - b * NB;
    float* o = nodein + (size_t)idx * 16;
    const float* xb = x + (size_t)b * 12 * NB + n;
#pragma unroll
    for (int k = 0; k < 12; ++k) o[k] = xb[(size_t)k * NB];
    o[12] = pos[2 * n];
    o[13] = pos[2 * n + 1];
    o[14] = 0.0f; o[15] = 0.0f;
}

// ---------------- fused embedding: t1 = swish(nodein@W1+b1); hf = swish(t1@W2+b2) ----------------
__global__ __launch_bounds__(256, 4)
void k_emb(const float* __restrict__ nodein, const float* __restrict__ w1,
           const float* __restrict__ b1, const unsigned short* __restrict__ wT2,
           const float* __restrict__ b2, float* __restrict__ hf) {
    __shared__ float xs[16][14];
    __shared__ char t1s[4096];
    int t = threadIdx.x;
    int rt = blockIdx.x * 16;
    if (t < 224) {
        int r = t / 14, k = t - r * 14;
        xs[r][k] = nodein[(size_t)(rt + r) * 16 + k];
    }
    __syncthreads();
    {
        int f = t & 127, rblk = t >> 7;
        float wreg[14];
#pragma unroll
        for (int k = 0; k < 14; ++k) wreg[k] = w1[k * HF + f];
        float bv = b1[f];
#pragma unroll
        for (int i = 0; i < 8; ++i) {
            int row = rblk * 8 + i;
            float acc = bv;
#pragma unroll
            for (int k = 0; k < 14; ++k) acc = fmaf(xs[row][k], wreg[k], acc);
            int addr = (row * 256 + f * 2) ^ ((row & 7) << 4);
            *(unsigned short*)(t1s + addr) = f2b(swishf(acc));
        }
    }
    __syncthreads();
    int wave = t >> 6, lane = t & 63, lr = lane & 15, lg = lane >> 4;
    int fb = wave * 32;
    f32x4 acc[2];
    acc[0] = (f32x4)0.0f; acc[1] = (f32x4)0.0f;
#pragma unroll
    for (int kc = 0; kc < 4; ++kc) {
        int k0 = kc * 32 + lg * 8;
        bf16x8 a = *(const bf16x8*)(t1s + ((lr * 256 + k0 * 2) ^ ((lr & 7) << 4)));
#pragma unroll
        for (int j = 0; j < 2; ++j) {
            bf16x8 b = *(const bf16x8*)(wT2 + (size_t)(fb + j * 16 + lr) * HF + k0);
            acc[j] = MFMA16(a, b, acc[j]);
        }
    }
#pragma unroll
    for (int j = 0; j < 2; ++j) {
        int f = fb + j * 16 + lr;
        float bv = b2[f];
#pragma unroll
        for (int r = 0; r < 4; ++r) {
            size_t o = (size_t)(rt + lg * 4 + r) * HF + f;
            hf[o] = swishf(acc[j][r] + bv);
        }
    }
}

// ---------------- A/S projection (norm-on-read) with fused Au ----------------
// A = bf16(norm(hf)@W1a + nodein@W1u) ; S = bf16(norm(hf)@W1b - nodein@W1u)
__global__ __launch_bounds__(256, 4)
void k_as(const float* __restrict__ hf, const float* __restrict__ mraw,
          const unsigned short* __restrict__ wA, const unsigned short* __restrict__ wB,
          const float* __restrict__ nodein, const float* __restrict__ w1u,
          unsigned short* __restrict__ A, unsigned short* __restrict__ S) {
    __shared__ float w1s[12][128];
    __shared__ float nis[16][12];
    __shared__ float mus[128], rss[128];
    int t = threadIdx.x, wave = t >> 6, lane = t & 63, lr = lane & 15, lg = lane >> 4;
    int rt = blockIdx.x * 16;
    int b = blockIdx.x / (NB / 16);
    int fb = wave * 32;
    for (int i = t; i < 12 * 128; i += 256) w1s[i >> 7][i & 127] = w1u[i];
    if (t < 192) {
        int r = t / 12, k = t - (t / 12) * 12;
        nis[r][k] = nodein[(size_t)(rt + r) * 16 + k];
    }
    load_musig(mraw, b, t, mus, rss);
    __syncthreads();
    f32x4 accA[2], accS[2];
    accA[0] = (f32x4)0.0f; accA[1] = (f32x4)0.0f;
    accS[0] = (f32x4)0.0f; accS[1] = (f32x4)0.0f;
#pragma unroll
    for (int kc = 0; kc < 4; ++kc) {
        int k0 = kc * 32 + lg * 8;
        bf16x8 a = norm_frag(hf + (size_t)(rt + lr) * HF + k0, mus, rss, k0);
#pragma unroll
        for (int j = 0; j < 2; ++j) {
            bf16x8 bA = *(const bf16x8*)(wA + (size_t)(fb + j * 16 + lr) * HF + k0);
            accA[j] = MFMA16(a, bA, accA[j]);
            bf16x8 bS = *(const bf16x8*)(wB + (size_t)(fb + j * 16 + lr) * HF + k0);
            accS[j] = MFMA16(a, bS, accS[j]);
        }
    }
#pragma unroll
    for (int j = 0; j < 2; ++j) {
        int f = fb + j * 16 + lr;
        float au[4] = {0.f, 0.f, 0.f, 0.f};
#pragma unroll
        for (int k = 0; k < 12; ++k) {
            float wv = w1s[k][f];
#pragma unroll
            for (int r = 0; r < 4; ++r) au[r] = fmaf(nis[lg * 4 + r][k], wv, au[r]);
        }
#pragma unroll
        for (int r = 0; r < 4; ++r) {
            size_t o = (size_t)(rt + lg * 4 + r) * HF + f;
            A[o] = f2b(accA[j][r] + au[r]);
            S[o] = f2b(accS[j][r] - au[r]);
        }
    }
}

// ---------------- fused message+aggregate+update (3-offset groups, small LDS,
// single masked path, compact rolled group loop):
// agg = (1/deg) sum_off swish(swish(A+S+D)@W2m + b2m)
// t1  = swish(norm(hf)@W1a + agg@W1b + b1u)
// v   = swish(t1@W2u + b2u) + norm(hf); hf <- v; stats -> atomicAdd msr ----------------
__global__ __launch_bounds__(256, 4)
void k_aggupd(const unsigned short* __restrict__ Ab, const unsigned short* __restrict__ Sb,
              const unsigned short* __restrict__ wT2, const float* __restrict__ b2m,
              const float* __restrict__ b1m, const float* __restrict__ w1d,
              float* __restrict__ hf, const float* __restrict__ mraw,
              const unsigned short* __restrict__ w1a, const unsigned short* __restrict__ w1b,
              const unsigned short* __restrict__ w2u, const float* __restrict__ b1u,
              const float* __restrict__ b2u, float* __restrict__ msr) {
    __shared__ float dsb[3][128];
    __shared__ float mus[128], rss[128];
    __shared__ char exb[3 * 4096];       // 3-offset z groups; phase3: agg @0, t1 @4096
    int t = threadIdx.x, kq = t >> 6, lane = t & 63, lr = lane & 15, lg = lane >> 4;
    int bx = blockIdx.x;
    int b = bx / (NB / 16), tile = bx % (NB / 16);
    int rt = tile * 16;                  // LOCAL row within batch (16 | 96)
    int fb = kq * 32;
    size_t bN = (size_t)b * NB;
    int R = rt / GW, C0 = rt % GW;

    if (t < 128) {
        float bb = b1m[t], wd = w1d[t];
        dsb[0][t] = bb;
        dsb[1][t] = fmaf(1.0f / 95.0f, wd, bb);
        dsb[2][t] = fmaf(1.4142135623730951f / 95.0f, wd, bb);
    }
    load_musig(mraw, b, t, mus, rss);
    bf16x8 w2f[2][4];
#pragma unroll
    for (int j = 0; j < 2; ++j)
#pragma unroll
        for (int kc = 0; kc < 4; ++kc)
            w2f[j][kc] = *(const bf16x8*)(wT2 + (size_t)(fb + j * 16 + lr) * HF
                                          + kc * 32 + lg * 8);
    int rowA = rt + lr;
    float Af[8];
    {
        bf16x8 av = *(const bf16x8*)(Ab + (bN + rowA) * HF + kq * 32 + lg * 8);
#pragma unroll
        for (int e = 0; e < 8; ++e) Af[e] = b2f((unsigned short)av[e]);
    }
    float b2r[2] = { b2m[fb + lr], b2m[fb + 16 + lr] };
    int lofs = lane * 16;
    // column masks per (dc, r), hoisted out of the offset loops
    bool mC[3][4];
#pragma unroll
    for (int dcI = 0; dcI < 3; ++dcI)
#pragma unroll
        for (int r = 0; r < 4; ++r)
            mC[dcI][r] = (unsigned)(C0 + lg * 4 + r + dcI - 1) < (unsigned)GW;
    __syncthreads();   // dsb/mus ready

    f32x4 agg2[2];
    agg2[0] = (f32x4)0.0f; agg2[1] = (f32x4)0.0f;
    bf16x8 sv;
    {
        int src = min(max(rowA - 97, 0), NB - 1);
        sv = *(const bf16x8*)(Sb + (bN + src) * HF + kq * 32 + lg * 8);
    }
#pragma unroll 1
    for (int g = 0; g < 3; ++g) {
        int dr = g - 1;                    // offsets g*3..g*3+2 share dr
        bool rOK = (unsigned)(R + dr) < (unsigned)GH;
        // ---- z for offsets 3g..3g+2 (own k-quarter) ----
#pragma unroll
        for (int oi = 0; oi < 3; ++oi) {
            int off = g * 3 + oi;
            int dc = oi - 1;
            int dd = dr * dr + dc * dc;
            bf16x8 cur = sv;
            if (off < 8) {
                int no = off + 1;
                int dnn = (no / 3 - 1) * GW + (no % 3 - 1);
                int src = min(max(rowA + dnn, 0), NB - 1);
                sv = *(const bf16x8*)(Sb + (bN + src) * HF + kq * 32 + lg * 8);
            }
            const float* dp = &dsb[dd][kq * 32 + lg * 8];
            union { bf16x8 v; unsigned u[4]; } cu; cu.v = cur;
            union { bf16x8 v; unsigned u[4]; } az;
#pragma unroll
            for (int q = 0; q < 4; ++q) {
                float sl = __uint_as_float(cu.u[q] << 16);
                float sh = __uint_as_float(cu.u[q] & 0xffff0000u);
                float zl = swishf(Af[2 * q]     + sl + dp[2 * q]);
                float zh = swishf(Af[2 * q + 1] + sh + dp[2 * q + 1]);
                az.u[q] = pk2(zl, zh);
            }
            *(bf16x8*)(exb + oi * 4096 + kq * 1024 + lofs) = az.v;
        }
        __syncthreads();
        // ---- MFMA + masked epilogue for offsets 3g..3g+2 ----
#pragma unroll
        for (int oi = 0; oi < 3; ++oi) {
            f32x4 acc[2];
            acc[0] = (f32x4)0.0f; acc[1] = (f32x4)0.0f;
#pragma unroll
            for (int kc = 0; kc < 4; ++kc) {
                bf16x8 a = *(const bf16x8*)(exb + oi * 4096 + kc * 1024 + lofs);
                acc[0] = MFMA16(a, w2f[0][kc], acc[0]);
                acc[1] = MFMA16(a, w2f[1][kc], acc[1]);
            }
#pragma unroll
            for (int j = 0; j < 2; ++j)
#pragma unroll
                for (int r = 0; r < 4; ++r) {
                    if (rOK && mC[oi][r])
                        agg2[j][r] += swishf(acc[j][r] + b2r[j]);
                }
        }
        __syncthreads();
    }

    // ---- agg tile -> LDS (bf16, swizzled, rows local 0..15) ----
    float nr = 1.0f + (R > 0) + (R < GH - 1);
#pragma unroll
    for (int j = 0; j < 2; ++j)
#pragma unroll
        for (int r = 0; r < 4; ++r) {
            int row = lg * 4 + r;
            int C = C0 + row;
            float nc = 1.0f + (C > 0) + (C < GW - 1);
            float v = __fdividef(agg2[j][r], nr * nc);
            int f = fb + j * 16 + lr;
            int addr = (row * 256 + f * 2) ^ ((row & 7) << 4);
            *(unsigned short*)(exb + addr) = f2b(v);
        }
    __syncthreads();

    // ---- update GEMM1 (norm(hf), agg) — hf rows are GLOBAL (bN + rt) ----
    f32x4 acc[2];
    acc[0] = (f32x4)0.0f; acc[1] = (f32x4)0.0f;
#pragma unroll
    for (int kc = 0; kc < 4; ++kc) {
        int k0 = kc * 32 + lg * 8;
        bf16x8 a1 = norm_frag(hf + (bN + rt + lr) * HF + k0, mus, rss, k0);
        bf16x8 a2 = *(const bf16x8*)(exb + ((lr * 256 + k0 * 2) ^ ((lr & 7) << 4)));
#pragma unroll
        for (int j = 0; j < 2; ++j) {
            bf16x8 bA = *(const bf16x8*)(w1a + (size_t)(fb + j * 16 + lr) * HF + k0);
            acc[j] = MFMA16(a1, bA, acc[j]);
            bf16x8 bB = *(const bf16x8*)(w1b + (size_t)(fb + j * 16 + lr) * HF + k0);
            acc[j] = MFMA16(a2, bB, acc[j]);
        }
    }
    // t1 = swish(acc + b1u) -> swizzled LDS @4096
#pragma unroll
    for (int j = 0; j < 2; ++j) {
        int col = fb + j * 16 + lr;
        float bv = b1u[col];
#pragma unroll
        for (int r = 0; r < 4; ++r) {
            int row = lg * 4 + r;
            int addr = (row * 256 + col * 2) ^ ((row & 7) << 4);
            *(unsigned short*)(exb + 4096 + addr) = f2b(swishf(acc[j][r] + bv));
        }
    }
    __syncthreads();
    // GEMM2
    f32x4 acc2[2];
    acc2[0] = (f32x4)0.0f; acc2[1] = (f32x4)0.0f;
#pragma unroll
    for (int kc = 0; kc < 4; ++kc) {
        int k0 = kc * 32 + lg * 8;
        bf16x8 a = *(const bf16x8*)(exb + 4096 + ((lr * 256 + k0 * 2) ^ ((lr & 7) << 4)));
#pragma unroll
        for (int j = 0; j < 2; ++j) {
            bf16x8 bfr = *(const bf16x8*)(w2u + (size_t)(fb + j * 16 + lr) * HF + k0);
            acc2[j] = MFMA16(a, bfr, acc2[j]);
        }
    }
#pragma unroll
    for (int j = 0; j < 2; ++j) {
        int f = fb + j * 16 + lr;
        float bv = b2u[f];
        float mu = mus[f], rs = rss[f];
        float s1 = 0.f, s2 = 0.f;
#pragma unroll
        for (int r = 0; r < 4; ++r) {
            size_t o = (bN + rt + lg * 4 + r) * HF + f;
            float v = swishf(acc2[j][r] + bv) + (hf[o] - mu) * rs;
            hf[o] = v;
            s1 += v; s2 += v * v;
        }
        s1 += __shfl_xor(s1, 16); s1 += __shfl_xor(s1, 32);
        s2 += __shfl_xor(s2, 16); s2 += __shfl_xor(s2, 32);
        if (lg == 0) {
            atomicAdd(&msr[b * 128 + f], s1);
            atomicAdd(&msr[256 + b * 128 + f], s2);
        }
    }
}

// ---------------- fused output head (norm-on-read):
// g1 = swish(norm(hf)@W1+b1); out = x[:,-1] + g1@W2 + b2 ----------------
__global__ __launch_bounds__(256, 4)
void k_out(const float* __restrict__ hf, const float* __restrict__ mraw,
           const unsigned short* __restrict__ wT1, const float* __restrict__ b1,
           const float* __restrict__ w2, const float* __restrict__ b2,
           const float* __restrict__ x, float* __restrict__ out) {
    __shared__ float g1s[16][132];
    __shared__ float w2s[384];
    __shared__ float mus[128], rss[128];
    int t = threadIdx.x, wave = t >> 6, lane = t & 63, lr = lane & 15, lg = lane >> 4;
    int rt = blockIdx.x * 16;
    int b = blockIdx.x / (NB / 16);
    int fb = wave * 32;
    for (int i = t; i < 384; i += 256) w2s[i] = w2[i];
    load_musig(mraw, b, t, mus, rss);
    __syncthreads();
    f32x4 acc[2];
    acc[0] = (f32x4)0.0f; acc[1] = (f32x4)0.0f;
#pragma unroll
    for (int kc = 0; kc < 4; ++kc) {
        int k0 = kc * 32 + lg * 8;
        bf16x8 a = norm_frag(hf + (size_t)(rt + lr) * HF + k0, mus, rss, k0);
#pragma unroll
        for (int j = 0; j < 2; ++j) {
            bf16x8 bfr = *(const bf16x8*)(wT1 + (size_t)(fb + j * 16 + lr) * HF + k0);
            acc[j] = MFMA16(a, bfr, acc[j]);
        }
    }
#pragma unroll
    for (int j = 0; j < 2; ++j) {
        int f = fb + j * 16 + lr;
        float bv = b1[f];
#pragma unroll
        for (int r = 0; r < 4; ++r)
            g1s[lg * 4 + r][f] = swishf(acc[j][r] + bv);
    }
    __syncthreads();
    if (t < 48) {
        int r = t / 3, c = t - (t / 3) * 3;
        int row = rt + r;
        int bb = row / NB, n = row - bb * NB;
        float a = b2[c];
#pragma unroll 8
        for (int k = 0; k < HF; ++k) a = fmaf(g1s[r][k], w2s[k * 3 + c], a);
        float xv = x[(((size_t)bb * 4 + 3) * 3 + c) * NB + n];
        out[((size_t)bb * 3 + c) * NB + n] = a + xv;
    }
}

extern "C" void kernel_launch(void* const* d_in, const int* in_sizes, int n_in,
                              void* d_out, int out_size, void* d_ws, size_t ws_size,
                              hipStream_t stream) {
    const float* x      = (const float*)d_in[0];
    const float* pos    = (const float*)d_in[3];
    const float* emb_w1 = (const float*)d_in[4];
    const float* emb_b1 = (const float*)d_in[5];
    const float* emb_b2 = (const float*)d_in[7];
    const float* msg_w1 = (const float*)d_in[8];
    const float* msg_b1 = (const float*)d_in[9];
    const float* msg_b2 = (const float*)d_in[11];
    const float* upd_b1 = (const float*)d_in[13];
    const float* upd_b2 = (const float*)d_in[15];
    const float* out_b1 = (const float*)d_in[17];
    const float* out_w2 = (const float*)d_in[18];
    const float* out_b2 = (const float*)d_in[19];

    float* w = (float*)d_ws;
    size_t off = 0;
    auto alloc = [&](size_t n) { float* p = w + off; off += n; return p; };
    float* nodein  = alloc((size_t)MROWS * 16);
    float* hf      = alloc((size_t)MROWS * HF);
    float* msr     = alloc((size_t)LAYERS * 512);   // per-layer [sum|sumsq] accumulators
    unsigned short* Abf  = (unsigned short*)alloc((size_t)MROWS * 64);
    unsigned short* Sbf  = (unsigned short*)alloc((size_t)MROWS * 64);
    unsigned short* wT   = (unsigned short*)alloc((size_t)38 * 16384 / 2);
    (void)ws_size; (void)in_sizes; (void)n_in; (void)out_size;

    k_prep<<<38, 256, 0, stream>>>((const float*)d_in[6], (const float*)d_in[16],
                                   msg_w1, (const float*)d_in[10],
                                   (const float*)d_in[12], (const float*)d_in[14], wT);
    k_build<<<(MROWS + 255) / 256, 256, 0, stream>>>(x, pos, nodein, msr);
    k_emb<<<1152, 256, 0, stream>>>(nodein, emb_w1, emb_b1, wT + 0 * 16384, emb_b2, hf);
    for (int l = 0; l < LAYERS; ++l) {
        const unsigned short* wL = wT + (size_t)(2 + 6 * l) * 16384;
        const float* W1 = msg_w1 + (size_t)l * 269 * HF;
        const float* mprev = (l == 0) ? nullptr : msr + (size_t)(l - 1) * 512;
        k_as<<<1152, 256, 0, stream>>>(hf, mprev, wL + 0 * 16384, wL + 1 * 16384,
                                       nodein, W1 + 256 * HF, Abf, Sbf);
        k_aggupd<<<1152, 256, 0, stream>>>(Abf, Sbf, wL + 2 * 16384, msg_b2 + l * HF,
                                           msg_b1 + l * HF, W1 + 268 * HF,
                                           hf, mprev,
                                           wL + 3 * 16384, wL + 4 * 16384,
                                           wL + 5 * 16384, upd_b1 + l * HF,
                                           upd_b2 + l * HF, msr + (size_t)l * 512);
    }
    k_out<<<1152, 256, 0, stream>>>(hf, msr + (size_t)(LAYERS - 1) * 512,
                                    wT + 1 * 16384, out_b1, out_w2, out_b2,
                                    x, (float*)d_out);
}